// Round 12
// baseline (229.823 us; speedup 1.0000x reference)
//
#include <hip/hip_runtime.h>
#include <math.h>

#define EPSV 0.1f
#define MAX_ITER 10
constexpr int NB       = 16;
constexpr int IN_SIZE  = 1024;
constexpr int IN_DIM   = 1024;
constexpr int HEADS    = 4;
constexpr int OUT_SIZE = 128;
constexpr int OUT_DIM  = 1024;

typedef __attribute__((ext_vector_type(8))) _Float16 f16x8;
typedef __attribute__((ext_vector_type(4))) float f32x4;

__device__ __forceinline__ unsigned cvth2(float lo, float hi) {
    _Float16 a = (_Float16)lo, b = (_Float16)hi;
    unsigned short ua = *(unsigned short*)&a, ub = *(unsigned short*)&b;
    return (unsigned)ua | ((unsigned)ub << 16);
}
__device__ __forceinline__ unsigned short cvth1(float f) {
    _Float16 a = (_Float16)f;
    return *(unsigned short*)&a;
}
__device__ __forceinline__ unsigned short bf16rne(float f) {
    unsigned a = __float_as_uint(f);
    return (unsigned short)((a + 0x7fffu + ((a >> 16) & 1u)) >> 16);
}

// ---------------------------------------------------------------------------
// MFMA fp16 GEMM, M fixed at 128. C = alpha*A*B^T (+variants). (unchanged)
// ---------------------------------------------------------------------------
template<int AMODE, bool B_F32, int CMODE, int NF, bool AKBLK, bool SWAP>
__global__ __launch_bounds__(256)
void mfma_gemm(const void* __restrict__ Ap, const void* __restrict__ Bp,
               const float* __restrict__ bias, void* __restrict__ Cp,
               const float* __restrict__ euv,
               int K, int lda, int ldb, int ldc, int div,
               long AsN, long AsM, long BsN, long BsM, long CsN, long CsM,
               long AkStride, float alpha)
{
    constexpr int BN  = NF * 32;
    constexpr int BKP = 40;
    const int z  = SWAP ? blockIdx.x : blockIdx.z;
    const int n0 = (SWAP ? blockIdx.z : blockIdx.x) * BN;
    const long aoff = (long)(z / div) * AsN + (long)(z % div) * AsM;
    const long boff = (long)(z / div) * BsN + (long)(z % div) * BsM;
    const long coff = (long)(z / div) * CsN + (long)(z % div) * CsM;

    __shared__ short As[128 * BKP];
    __shared__ short Bs[BN * BKP];
    __shared__ float ecv_s[128];

    const int t = threadIdx.x;
    const int lane = t & 63;
    const int w = t >> 6, wr = w >> 1, wc = w & 1;

    if (CMODE == 3 && t < 128) ecv_s[t] = euv[(long)z * 1152 + 1024 + t];

    f32x4 acc[4][NF];
    #pragma unroll
    for (int i = 0; i < 4; ++i)
        #pragma unroll
        for (int j = 0; j < NF; ++j) { acc[i][j].x = 0.f; acc[i][j].y = 0.f; acc[i][j].z = 0.f; acc[i][j].w = 0.f; }

    for (int k0 = 0; k0 < K; k0 += 32) {
        const long abase = AKBLK ? aoff + (long)(k0 >> 10) * AkStride + (k0 & 1023)
                                 : aoff + k0;
        const long bbase = boff + k0;
        #pragma unroll
        for (int itr = 0; itr < 2; ++itr) {
            const int idx = itr * 256 + t;
            const int row = idx >> 2, kq = idx & 3;
            uint4 p;
            if (AMODE == 2) {
                const uint4 e = *(const uint4*)((const short*)Ap + abase + (long)row * lda + kq * 8);
                const float* eup = euv + (long)z * 1152 + k0 + kq * 8;
                const float4 e0 = *(const float4*)eup, e1 = *(const float4*)(eup + 4);
                p.x = cvth2(__uint_as_float(e.x << 16) * e0.x, __uint_as_float(e.x & 0xffff0000u) * e0.y);
                p.y = cvth2(__uint_as_float(e.y << 16) * e0.z, __uint_as_float(e.y & 0xffff0000u) * e0.w);
                p.z = cvth2(__uint_as_float(e.z << 16) * e1.x, __uint_as_float(e.z & 0xffff0000u) * e1.y);
                p.w = cvth2(__uint_as_float(e.w << 16) * e1.z, __uint_as_float(e.w & 0xffff0000u) * e1.w);
            } else {
                p = *(const uint4*)((const short*)Ap + abase + (long)row * lda + kq * 8);
            }
            *(uint4*)&As[row * BKP + kq * 8] = p;
        }
        #pragma unroll
        for (int itr = 0; itr < BN / 64; ++itr) {
            const int idx = itr * 256 + t;
            const int row = idx >> 2, kq = idx & 3;
            uint4 p;
            if (B_F32) {
                const float* s = (const float*)Bp + bbase + (long)(n0 + row) * ldb + kq * 8;
                const float4 f0 = *(const float4*)s, f1 = *(const float4*)(s + 4);
                p.x = cvth2(f0.x, f0.y); p.y = cvth2(f0.z, f0.w);
                p.z = cvth2(f1.x, f1.y); p.w = cvth2(f1.z, f1.w);
            } else {
                p = *(const uint4*)((const short*)Bp + bbase + (long)(n0 + row) * ldb + kq * 8);
            }
            *(uint4*)&Bs[row * BKP + kq * 8] = p;
        }
        __syncthreads();

        f16x8 af[4], bfr[NF];
        #pragma unroll
        for (int mi = 0; mi < 4; ++mi)
            af[mi] = *(const f16x8*)&As[(wr * 64 + mi * 16 + (lane & 15)) * BKP + (lane >> 4) * 8];
        #pragma unroll
        for (int ni = 0; ni < NF; ++ni)
            bfr[ni] = *(const f16x8*)&Bs[(wc * (BN / 2) + ni * 16 + (lane & 15)) * BKP + (lane >> 4) * 8];
        #pragma unroll
        for (int mi = 0; mi < 4; ++mi)
            #pragma unroll
            for (int ni = 0; ni < NF; ++ni)
                acc[mi][ni] = __builtin_amdgcn_mfma_f32_16x16x32_f16(af[mi], bfr[ni], acc[mi][ni], 0, 0, 0);
        __syncthreads();
    }

    #pragma unroll
    for (int mi = 0; mi < 4; ++mi) {
        #pragma unroll
        for (int ni = 0; ni < NF; ++ni) {
            #pragma unroll
            for (int j = 0; j < 4; ++j) {
                const int row = wr * 64 + mi * 16 + (lane >> 4) * 4 + j;
                const int col = n0 + wc * (BN / 2) + ni * 16 + (lane & 15);
                float v = acc[mi][ni][j] * alpha;
                if (CMODE == 2) { v += bias[col]; v = fmaxf(v, 0.f); }
                if (CMODE == 3) v *= ecv_s[row];
                if (CMODE == 2 || CMODE == 4) ((float*)Cp)[coff + (long)row * ldc + col] = v;
                else ((unsigned short*)Cp)[coff + (long)row * ldc + col] = cvth1(v);
            }
        }
    }
}

// ---------------------------------------------------------------------------
__global__ __launch_bounds__(256)
void splitk_reduce(const float* __restrict__ part, const float* __restrict__ bias,
                   float* __restrict__ out)
{
    const long idx = ((long)blockIdx.x * 256 + threadIdx.x) * 4;
    const int o = (int)(idx & 1023);
    const float4 p0 = *(const float4*)(part + idx);
    const float4 p1 = *(const float4*)(part + 2097152 + idx);
    const float4 p2 = *(const float4*)(part + 2 * 2097152 + idx);
    const float4 p3 = *(const float4*)(part + 3 * 2097152 + idx);
    const float4 bv = *(const float4*)(bias + o);
    float4 r;
    r.x = fmaxf(p0.x + p1.x + p2.x + p3.x + bv.x, 0.f);
    r.y = fmaxf(p0.y + p1.y + p2.y + p3.y + bv.y, 0.f);
    r.z = fmaxf(p0.z + p1.z + p2.z + p3.z + bv.z, 0.f);
    r.w = fmaxf(p0.w + p1.w + p2.w + p3.w + bv.w, 0.f);
    *(float4*)(out + idx) = r;
}

// ---------------------------------------------------------------------------
// GEMM1 fused, BN=64 version: grid (64 tiles, 1, 16 i-chunks) = 1024 blocks
// = 4 blocks/CU (R10's 512 = 2/CU was latency-bound). Block computes
// [128 s][64 i], still holds ALL 128 s -> colmax/Mi identical values.
// XCD alignment preserved: linear id = bx + 64*bz -> XCD = bx%8 = tile%8.
// ---------------------------------------------------------------------------
__global__ __launch_bounds__(256)
void gemm1_exp(const float* __restrict__ otw, const float* __restrict__ x,
               unsigned short* __restrict__ ekb, float* __restrict__ MiB)
{
    constexpr int BKP = 40;
    const int zb = blockIdx.x;                // b = n*4+m  (XCD-aligned)
    const int nn = zb >> 2, mm = zb & 3;
    const float* A = otw + (long)mm * (OUT_SIZE * IN_DIM);   // [128][1024]
    const float* B = x   + (long)nn * (IN_SIZE * IN_DIM);    // [1024][1024]
    const int n0 = blockIdx.z * 64;           // i-chunk (64 wide)

    __shared__ short As[128 * BKP];
    __shared__ short Bs[64 * BKP];
    __shared__ float colmax[2][64];

    const int t = threadIdx.x;
    const int lane = t & 63;
    const int w = t >> 6, wr = w >> 1, wc = w & 1;

    f32x4 acc[4][2];
    #pragma unroll
    for (int i = 0; i < 4; ++i)
        #pragma unroll
        for (int j = 0; j < 2; ++j) { acc[i][j].x = 0.f; acc[i][j].y = 0.f; acc[i][j].z = 0.f; acc[i][j].w = 0.f; }

    for (int k0 = 0; k0 < 1024; k0 += 32) {
        // A-stage: 128 rows x 32 k (fp32 -> fp16)
        #pragma unroll
        for (int itr = 0; itr < 2; ++itr) {
            const int idx = itr * 256 + t;
            const int row = idx >> 2, kq = idx & 3;
            const float* s = A + (long)row * 1024 + k0 + kq * 8;
            const float4 f0 = *(const float4*)s, f1 = *(const float4*)(s + 4);
            uint4 p;
            p.x = cvth2(f0.x, f0.y); p.y = cvth2(f0.z, f0.w);
            p.z = cvth2(f1.x, f1.y); p.w = cvth2(f1.z, f1.w);
            *(uint4*)&As[row * BKP + kq * 8] = p;
        }
        // B-stage: 64 rows x 32 k (fp32 -> fp16), 1 iter
        {
            const int row = t >> 2, kq = t & 3;
            const float* s = B + (long)(n0 + row) * 1024 + k0 + kq * 8;
            const float4 f0 = *(const float4*)s, f1 = *(const float4*)(s + 4);
            uint4 p;
            p.x = cvth2(f0.x, f0.y); p.y = cvth2(f0.z, f0.w);
            p.z = cvth2(f1.x, f1.y); p.w = cvth2(f1.z, f1.w);
            *(uint4*)&Bs[row * BKP + kq * 8] = p;
        }
        __syncthreads();

        f16x8 af[4], bfr[2];
        #pragma unroll
        for (int mi = 0; mi < 4; ++mi)
            af[mi] = *(const f16x8*)&As[(wr * 64 + mi * 16 + (lane & 15)) * BKP + (lane >> 4) * 8];
        #pragma unroll
        for (int ni = 0; ni < 2; ++ni)
            bfr[ni] = *(const f16x8*)&Bs[(wc * 32 + ni * 16 + (lane & 15)) * BKP + (lane >> 4) * 8];
        #pragma unroll
        for (int mi = 0; mi < 4; ++mi)
            #pragma unroll
            for (int ni = 0; ni < 2; ++ni)
                acc[mi][ni] = __builtin_amdgcn_mfma_f32_16x16x32_f16(af[mi], bfr[ni], acc[mi][ni], 0, 0, 0);
        __syncthreads();
    }

    // ---- column (over s) max: 10*acc ----
    float lm[2];
    #pragma unroll
    for (int ni = 0; ni < 2; ++ni) {
        float mx = -INFINITY;
        #pragma unroll
        for (int mi = 0; mi < 4; ++mi)
            #pragma unroll
            for (int j = 0; j < 4; ++j) mx = fmaxf(mx, acc[mi][ni][j]);
        mx *= 10.0f;
        mx = fmaxf(mx, __shfl_xor(mx, 16, 64));
        mx = fmaxf(mx, __shfl_xor(mx, 32, 64));
        lm[ni] = mx;
    }
    if ((lane >> 4) == 0) {
        #pragma unroll
        for (int ni = 0; ni < 2; ++ni) colmax[wr][wc * 32 + ni * 16 + lane] = lm[ni];
    }
    __syncthreads();
    float cm[2];
    #pragma unroll
    for (int ni = 0; ni < 2; ++ni) {
        const int c = wc * 32 + ni * 16 + (lane & 15);
        cm[ni] = fmaxf(colmax[0][c], colmax[1][c]);
    }
    if (wr == 0 && (lane >> 4) == 0) {
        #pragma unroll
        for (int ni = 0; ni < 2; ++ni)
            MiB[(long)zb * 1024 + n0 + wc * 32 + ni * 16 + lane] = cm[ni];
    }
    // ---- ek = bf16(exp(10*acc - cm)) ----
    unsigned short* ekz = ekb + (long)zb * (OUT_SIZE * IN_SIZE);
    #pragma unroll
    for (int mi = 0; mi < 4; ++mi) {
        #pragma unroll
        for (int ni = 0; ni < 2; ++ni) {
            const int col = n0 + wc * 32 + ni * 16 + (lane & 15);
            #pragma unroll
            for (int j = 0; j < 4; ++j) {
                const int row = wr * 64 + mi * 16 + (lane >> 4) * 4 + j;
                ekz[(long)row * 1024 + col] = bf16rne(__expf(fmaf(acc[mi][ni][j], 10.f, -cm[ni])));
            }
        }
    }
}

// ---------------------------------------------------------------------------
__global__ __launch_bounds__(256)
void transpose_cvt(const float* __restrict__ x, unsigned short* __restrict__ xT)
{
    const int n = blockIdx.z, i0 = blockIdx.y * 64, d0 = blockIdx.x * 64;
    const float* xs = x + (long)n * (IN_SIZE * IN_DIM);
    unsigned short* xo = xT + (long)n * (IN_SIZE * IN_DIM);
    __shared__ float tile[64][65];
    const int t = threadIdx.x;
    const int r = t >> 4, c4 = (t & 15) * 4;
    #pragma unroll
    for (int rr = 0; rr < 4; ++rr) {
        const float4 v = *(const float4*)(xs + (long)(i0 + rr * 16 + r) * IN_DIM + d0 + c4);
        *(float4*)&tile[rr * 16 + r][c4] = v;
    }
    __syncthreads();
    #pragma unroll
    for (int rr = 0; rr < 4; ++rr) {
        const int dl = rr * 16 + r;
        ushort4 o;
        o.x = cvth1(tile[c4 + 0][dl]); o.y = cvth1(tile[c4 + 1][dl]);
        o.z = cvth1(tile[c4 + 2][dl]); o.w = cvth1(tile[c4 + 3][dl]);
        *(ushort4*)(xo + (long)(d0 + dl) * IN_SIZE + i0 + c4) = o;
    }
}

// ---------------------------------------------------------------------------
// Sinkhorn v5.1: LDS-resident split-tile (as R10) + fine-grained poll
// (s_sleep(1): sibling blocks run identical code, arrival skew is small;
// s_sleep(16)'s ~0.4us granularity was pure overshoot x 10 iters).
// ---------------------------------------------------------------------------
__global__ __launch_bounds__(512)
void sinkhorn_split(const unsigned short* __restrict__ ekb,
                    const float* __restrict__ MiB, float* __restrict__ euvB,
                    float* __restrict__ xchg, unsigned int* __restrict__ ctr)
{
    const int q = blockIdx.x;          // i-quarter 0..3
    const int b = blockIdx.z;          // tile 0..63
    const int t = threadIdx.x;
    const int lane = t & 63, w = t >> 6;

    __shared__ unsigned ekw[128 * 129];    // bf16-pairs, row stride 129 dw
    __shared__ float part_u[4][256];
    __shared__ float part_v[4][128];
    __shared__ float eu_l[256];
    __shared__ float v_s[128], ev_s[128];
    __shared__ float red8[8];
    __shared__ float wg_s;

    // ---- one-time ek load: [128 s][256 i-local] ----
    {
        const unsigned short* src = ekb + (long)b * 131072 + q * 256;
        #pragma unroll
        for (int j = 0; j < 8; ++j) {
            const int idx = t + 512 * j;          // 0..4095
            const int s = idx >> 5, c8 = (idx & 31) * 8;
            const uint4 p = *(const uint4*)(src + (long)s * 1024 + c8);
            const int bd = s * 129 + (c8 >> 1);
            ekw[bd] = p.x; ekw[bd + 1] = p.y; ekw[bd + 2] = p.z; ekw[bd + 3] = p.w;
        }
    }
    float mi_t = 0.f, u_reg = 0.f, w_t = 0.f;
    if (t < 256) mi_t = MiB[(long)b * 1024 + q * 256 + t];
    if (t < 128) v_s[t] = 0.f;
    __syncthreads();

    const float A0 = -2.0794415416798357f;  // log(128/1024)

    for (int it = 0; it < MAX_ITER; ++it) {
        // ---- vmx + ev (redundant in all blocks, identical) ----
        if (t < 128) {
            float xv = v_s[t];
            #pragma unroll
            for (int m = 1; m < 64; m <<= 1) xv = fmaxf(xv, __shfl_xor(xv, m, 64));
            if (lane == 0) red8[w] = xv;
        }
        __syncthreads();
        const float vmx = fmaxf(red8[0], red8[1]);
        if (t < 128) ev_s[t] = __expf(v_s[t] - vmx);
        __syncthreads();

        // ---- u-pass: local over all 128 s ----
        {
            const int p = t & 127, sq = t >> 7;
            float s0 = 0.f, s1 = 0.f;
            #pragma unroll
            for (int j = 0; j < 32; ++j) {
                const int s = sq * 32 + j;
                const unsigned e = ekw[s * 129 + p];
                const float evv = ev_s[s];
                s0 = fmaf(__uint_as_float(e << 16),          evv, s0);
                s1 = fmaf(__uint_as_float(e & 0xffff0000u),  evv, s1);
            }
            part_u[sq][2 * p]     = s0;
            part_u[sq][2 * p + 1] = s1;
        }
        __syncthreads();

        // ---- u update (t<256 owns i-local = t), local wmx ----
        if (t < 256) {
            const float S = part_u[0][t] + part_u[1][t] + part_u[2][t] + part_u[3][t];
            const float un = A0 - u_reg - mi_t - vmx - __logf(S);
            u_reg = un;
            w_t = mi_t + un;
            float wl = w_t;
            #pragma unroll
            for (int m = 1; m < 64; m <<= 1) wl = fmaxf(wl, __shfl_xor(wl, m, 64));
            if (lane == 0) red8[4 + w] = wl;
        }
        __syncthreads();
        const float wmx_l = fmaxf(fmaxf(red8[4], red8[5]), fmaxf(red8[6], red8[7]));
        if (t < 256) eu_l[t] = __expf(w_t - wmx_l);
        __syncthreads();

        // ---- v-pass: local partial column sums ----
        {
            const int s = t & 127, g = t >> 7;
            float acc = 0.f;
            #pragma unroll
            for (int j = 0; j < 32; ++j) {
                const int p = 32 * g + j;
                const unsigned e = ekw[s * 129 + p];
                const float2 eup = *(const float2*)&eu_l[2 * p];
                acc = fmaf(__uint_as_float(e << 16),         eup.x, acc);
                acc = fmaf(__uint_as_float(e & 0xffff0000u), eup.y, acc);
            }
            part_v[g][s] = acc;
        }
        __syncthreads();

        // ---- publish (cp_local, wmx_l) to slot, arrive, wait ----
        float* slot = xchg + ((long)(b * MAX_ITER + it) * 4 + q) * 160;
        if (t < 128) {
            const float cp_l = part_v[0][t] + part_v[1][t] + part_v[2][t] + part_v[3][t];
            __hip_atomic_store(slot + t, cp_l, __ATOMIC_RELAXED, __HIP_MEMORY_SCOPE_AGENT);
        }
        if (t == 0)
            __hip_atomic_store(slot + 128, wmx_l, __ATOMIC_RELAXED, __HIP_MEMORY_SCOPE_AGENT);
        __syncthreads();   // drains this block's stores (waitcnt before barrier)
        if (t == 0) {
            unsigned int* c = ctr + b * MAX_ITER + it;
            __hip_atomic_fetch_add(c, 1u, __ATOMIC_RELEASE, __HIP_MEMORY_SCOPE_AGENT);
            while (__hip_atomic_load(c, __ATOMIC_ACQUIRE, __HIP_MEMORY_SCOPE_AGENT) < 4u)
                __builtin_amdgcn_s_sleep(1);
        }
        __syncthreads();

        // ---- combine (identical in all 4 blocks) ----
        if (t < 128) {
            float* base = xchg + (long)(b * MAX_ITER + it) * 4 * 160;
            const float w0 = __hip_atomic_load(base + 0 * 160 + 128, __ATOMIC_RELAXED, __HIP_MEMORY_SCOPE_AGENT);
            const float w1 = __hip_atomic_load(base + 1 * 160 + 128, __ATOMIC_RELAXED, __HIP_MEMORY_SCOPE_AGENT);
            const float w2 = __hip_atomic_load(base + 2 * 160 + 128, __ATOMIC_RELAXED, __HIP_MEMORY_SCOPE_AGENT);
            const float w3 = __hip_atomic_load(base + 3 * 160 + 128, __ATOMIC_RELAXED, __HIP_MEMORY_SCOPE_AGENT);
            const float wg = fmaxf(fmaxf(w0, w1), fmaxf(w2, w3));
            const float c0 = __hip_atomic_load(base + 0 * 160 + t, __ATOMIC_RELAXED, __HIP_MEMORY_SCOPE_AGENT);
            const float c1 = __hip_atomic_load(base + 1 * 160 + t, __ATOMIC_RELAXED, __HIP_MEMORY_SCOPE_AGENT);
            const float c2 = __hip_atomic_load(base + 2 * 160 + t, __ATOMIC_RELAXED, __HIP_MEMORY_SCOPE_AGENT);
            const float c3 = __hip_atomic_load(base + 3 * 160 + t, __ATOMIC_RELAXED, __HIP_MEMORY_SCOPE_AGENT);
            const float cp = c0 * __expf(w0 - wg) + c1 * __expf(w1 - wg)
                           + c2 * __expf(w2 - wg) + c3 * __expf(w3 - wg);
            v_s[t] = -v_s[t] - wg - __logf(cp);
            if (t == 0) wg_s = wg;
        }
        __syncthreads();
    }

    // ---- rank-1 factors: eu (global-normalized), ecv ----
    const float wg = wg_s;
    if (t < 256) euvB[(long)b * 1152 + q * 256 + t] = __expf(w_t - wg);
    if (q == 0 && t < 128) euvB[(long)b * 1152 + 1024 + t] = __expf(v_s[t] + wg);
}

// ---------------------------------------------------------------------------
extern "C" void kernel_launch(void* const* d_in, const int* in_sizes, int n_in,
                              void* d_out, int out_size, void* d_ws, size_t ws_size,
                              hipStream_t stream)
{
    const float* x     = (const float*)d_in[0];   // [16][1024][1024]
    const float* otw   = (const float*)d_in[1];   // [4][128][1024]
    const float* lin_w = (const float*)d_in[2];   // [1024][4096]
    const float* lin_b = (const float*)d_in[3];   // [1024]
    float* out = (float*)d_out;                   // [16][128][1024] fp32 (8 MB)

    // ws (64 MB): [0,32M) xT fp16 (dead after GEMM2 -> split-K partials)
    //             [32M,48M) ek bf16; [48M,64M) feat fp16
    unsigned short* xT   = (unsigned short*)d_ws;
    unsigned short* ekb  = xT + 16777216;
    unsigned short* feat = ekb + 8388608;
    float* partial = (float*)d_ws;                // [4][16][128][1024] f32
    // d_out scratch (fully overwritten by splitk_reduce):
    //   Mi [64][1024] @0 ; euv [64][1152] @65536 ; xchg [64][10][4][160] @147456 ;
    //   ctr [64][10] u32 @557056
    float* MiB  = (float*)d_out;
    float* euvB = MiB + 65536;
    float* xchg = MiB + 147456;
    unsigned int* ctrB = (unsigned int*)(MiB + 557056);

    // reset arrival counters (stream-ordered, capture-legal)
    hipMemsetAsync(ctrB, 0, 64 * MAX_ITER * sizeof(unsigned int), stream);

    // 0) x -> xT fp16
    transpose_cvt<<<dim3(16, 16, NB), 256, 0, stream>>>(x, xT);

    // 1) fused K-GEMM + colmax + exp -> ek bf16, Mi (BN=64, 4 blocks/CU)
    gemm1_exp<<<dim3(64, 1, 16), 256, 0, stream>>>(otw, x, ekb, MiB);

    // 2) Sinkhorn: 256 blocks, LDS-resident ek slices + per-iter handshake
    sinkhorn_split<<<dim3(4, 1, 64), 512, 0, stream>>>(ekb, MiB, euvB, xchg, ctrB);

    // 3) feat[b][s][d] = sum_i (ek*eu)[s][i] * xT[n][d][i], epilogue *ecv[s]
    //    NF=2, grid (64,1,16) = 4 blocks/CU, XCD-aligned
    mfma_gemm<2, false, 3, 2, false, true><<<dim3(64, 1, 16), 256, 0, stream>>>(
        ekb, xT, nullptr, feat, euvB,
        1024, 1024, 1024, 1024, 4,
        524288, 131072, 1048576, 0, 524288, 131072, 0, 1.0f);

    // 4) split-K x4 GEMM3
    mfma_gemm<0, true, 4, 2, false, false><<<dim3(16, 1, 64), 256, 0, stream>>>(
        feat, lin_w, nullptr, partial, nullptr,
        1024, 1024, 4096, 1024, 16,
        131072, 524288, 1024, 0, 2097152, 131072, 0, 1.0f);

    // 5) out = relu(sum_ks partial + bias)
    splitk_reduce<<<dim3(2048), 256, 0, stream>>>(partial, lin_b, out);
}

// Round 13
// 223.186 us; speedup vs baseline: 1.0297x; 1.0297x over previous
//
#include <hip/hip_runtime.h>
#include <math.h>

#define EPSV 0.1f
#define MAX_ITER 10
constexpr int NB       = 16;
constexpr int IN_SIZE  = 1024;
constexpr int IN_DIM   = 1024;
constexpr int HEADS    = 4;
constexpr int OUT_SIZE = 128;
constexpr int OUT_DIM  = 1024;

typedef __attribute__((ext_vector_type(8))) _Float16 f16x8;
typedef __attribute__((ext_vector_type(4))) float f32x4;

__device__ __forceinline__ unsigned cvth2(float lo, float hi) {
    _Float16 a = (_Float16)lo, b = (_Float16)hi;
    unsigned short ua = *(unsigned short*)&a, ub = *(unsigned short*)&b;
    return (unsigned)ua | ((unsigned)ub << 16);
}
__device__ __forceinline__ unsigned short cvth1(float f) {
    _Float16 a = (_Float16)f;
    return *(unsigned short*)&a;
}
__device__ __forceinline__ unsigned short bf16rne(float f) {
    unsigned a = __float_as_uint(f);
    return (unsigned short)((a + 0x7fffu + ((a >> 16) & 1u)) >> 16);
}

// ---------------------------------------------------------------------------
// MFMA fp16 GEMM, M fixed at 128. C = alpha*A*B^T (+variants).
// AMODE: 0 = A fp16 passthrough (only mode used now)
// B_F32: B fp32 -> fp16 in-flight, else fp16 passthrough
// CMODE: 1 = fp16 store, 2 = f32 + bias + relu, 4 = f32 raw (split-K partial)
// SWAP : batch index from blockIdx.x (XCD-aligned), n0 from blockIdx.z.
// ---------------------------------------------------------------------------
template<int AMODE, bool B_F32, int CMODE, int NF, bool AKBLK, bool SWAP>
__global__ __launch_bounds__(256)
void mfma_gemm(const void* __restrict__ Ap, const void* __restrict__ Bp,
               const float* __restrict__ bias, void* __restrict__ Cp,
               int K, int lda, int ldb, int ldc, int div,
               long AsN, long AsM, long BsN, long BsM, long CsN, long CsM,
               long AkStride, float alpha)
{
    constexpr int BN  = NF * 32;
    constexpr int BKP = 40;
    const int z  = SWAP ? blockIdx.x : blockIdx.z;
    const int n0 = (SWAP ? blockIdx.z : blockIdx.x) * BN;
    const long aoff = (long)(z / div) * AsN + (long)(z % div) * AsM;
    const long boff = (long)(z / div) * BsN + (long)(z % div) * BsM;
    const long coff = (long)(z / div) * CsN + (long)(z % div) * CsM;

    __shared__ short As[128 * BKP];
    __shared__ short Bs[BN * BKP];

    const int t = threadIdx.x;
    const int lane = t & 63;
    const int w = t >> 6, wr = w >> 1, wc = w & 1;

    f32x4 acc[4][NF];
    #pragma unroll
    for (int i = 0; i < 4; ++i)
        #pragma unroll
        for (int j = 0; j < NF; ++j) { acc[i][j].x = 0.f; acc[i][j].y = 0.f; acc[i][j].z = 0.f; acc[i][j].w = 0.f; }

    for (int k0 = 0; k0 < K; k0 += 32) {
        const long abase = AKBLK ? aoff + (long)(k0 >> 10) * AkStride + (k0 & 1023)
                                 : aoff + k0;
        const long bbase = boff + k0;
        // ---- stage A (128 x 32, fp16 passthrough) ----
        #pragma unroll
        for (int itr = 0; itr < 2; ++itr) {
            const int idx = itr * 256 + t;
            const int row = idx >> 2, kq = idx & 3;
            const uint4 p = *(const uint4*)((const short*)Ap + abase + (long)row * lda + kq * 8);
            *(uint4*)&As[row * BKP + kq * 8] = p;
        }
        // ---- stage B (BN x 32) ----
        #pragma unroll
        for (int itr = 0; itr < BN / 64; ++itr) {
            const int idx = itr * 256 + t;
            const int row = idx >> 2, kq = idx & 3;
            uint4 p;
            if (B_F32) {
                const float* s = (const float*)Bp + bbase + (long)(n0 + row) * ldb + kq * 8;
                const float4 f0 = *(const float4*)s, f1 = *(const float4*)(s + 4);
                p.x = cvth2(f0.x, f0.y); p.y = cvth2(f0.z, f0.w);
                p.z = cvth2(f1.x, f1.y); p.w = cvth2(f1.z, f1.w);
            } else {
                p = *(const uint4*)((const short*)Bp + bbase + (long)(n0 + row) * ldb + kq * 8);
            }
            *(uint4*)&Bs[row * BKP + kq * 8] = p;
        }
        __syncthreads();

        f16x8 af[4], bfr[NF];
        #pragma unroll
        for (int mi = 0; mi < 4; ++mi)
            af[mi] = *(const f16x8*)&As[(wr * 64 + mi * 16 + (lane & 15)) * BKP + (lane >> 4) * 8];
        #pragma unroll
        for (int ni = 0; ni < NF; ++ni)
            bfr[ni] = *(const f16x8*)&Bs[(wc * (BN / 2) + ni * 16 + (lane & 15)) * BKP + (lane >> 4) * 8];
        #pragma unroll
        for (int mi = 0; mi < 4; ++mi)
            #pragma unroll
            for (int ni = 0; ni < NF; ++ni)
                acc[mi][ni] = __builtin_amdgcn_mfma_f32_16x16x32_f16(af[mi], bfr[ni], acc[mi][ni], 0, 0, 0);
        __syncthreads();
    }

    #pragma unroll
    for (int mi = 0; mi < 4; ++mi) {
        #pragma unroll
        for (int ni = 0; ni < NF; ++ni) {
            #pragma unroll
            for (int j = 0; j < 4; ++j) {
                const int row = wr * 64 + mi * 16 + (lane >> 4) * 4 + j;
                const int col = n0 + wc * (BN / 2) + ni * 16 + (lane & 15);
                float v = acc[mi][ni][j] * alpha;
                if (CMODE == 2) { v += bias[col]; v = fmaxf(v, 0.f); }
                if (CMODE == 2 || CMODE == 4) ((float*)Cp)[coff + (long)row * ldc + col] = v;
                else ((unsigned short*)Cp)[coff + (long)row * ldc + col] = cvth1(v);
            }
        }
    }
}

// ---------------------------------------------------------------------------
__global__ __launch_bounds__(256)
void splitk_reduce(const float* __restrict__ part, const float* __restrict__ bias,
                   float* __restrict__ out)
{
    const long idx = ((long)blockIdx.x * 256 + threadIdx.x) * 4;
    const int o = (int)(idx & 1023);
    const float4 p0 = *(const float4*)(part + idx);
    const float4 p1 = *(const float4*)(part + 2097152 + idx);
    const float4 p2 = *(const float4*)(part + 2 * 2097152 + idx);
    const float4 p3 = *(const float4*)(part + 3 * 2097152 + idx);
    const float4 bv = *(const float4*)(bias + o);
    float4 r;
    r.x = fmaxf(p0.x + p1.x + p2.x + p3.x + bv.x, 0.f);
    r.y = fmaxf(p0.y + p1.y + p2.y + p3.y + bv.y, 0.f);
    r.z = fmaxf(p0.z + p1.z + p2.z + p3.z + bv.z, 0.f);
    r.w = fmaxf(p0.w + p1.w + p2.w + p3.w + bv.w, 0.f);
    *(float4*)(out + idx) = r;
}

// ---------------------------------------------------------------------------
// otw fp32 -> fp16 (one-time, 2 MB): lets gemm1 A-stage be a pure copy.
// ---------------------------------------------------------------------------
__global__ __launch_bounds__(256)
void cvt_otw(const float* __restrict__ in, unsigned short* __restrict__ out)
{
    const long i8 = ((long)blockIdx.x * 256 + threadIdx.x) * 8;
    const float4 f0 = *(const float4*)(in + i8), f1 = *(const float4*)(in + i8 + 4);
    uint4 p;
    p.x = cvth2(f0.x, f0.y); p.y = cvth2(f0.z, f0.w);
    p.z = cvth2(f1.x, f1.y); p.w = cvth2(f1.z, f1.w);
    *(uint4*)(out + i8) = p;
}

// ---------------------------------------------------------------------------
// GEMM1 fused (R10 tiling: BN=128, grid (64,1,8), 2 blocks/CU), fp16 A.
// Computes K = 10*otw.x^T per (b, 128-i chunk); colmax over ALL 128 s ->
// Mi; writes ek = bf16(exp(K - Mi)). XCD-aligned: tile = blockIdx.x.
// ---------------------------------------------------------------------------
__global__ __launch_bounds__(256)
void gemm1_exp(const unsigned short* __restrict__ otwH, const float* __restrict__ x,
               unsigned short* __restrict__ ekb, float* __restrict__ MiB)
{
    constexpr int BKP = 40;
    const int zb = blockIdx.x;                // b = n*4+m  (XCD-aligned)
    const int nn = zb >> 2, mm = zb & 3;
    const unsigned short* A = otwH + (long)mm * (OUT_SIZE * IN_DIM);  // [128][1024] fp16
    const float* B = x + (long)nn * (IN_SIZE * IN_DIM);               // [1024][1024] fp32
    const int n0 = blockIdx.z * 128;          // i-chunk

    __shared__ short As[128 * BKP];
    __shared__ short Bs[128 * BKP];
    __shared__ float colmax[2][128];

    const int t = threadIdx.x;
    const int lane = t & 63;
    const int w = t >> 6, wr = w >> 1, wc = w & 1;

    f32x4 acc[4][4];
    #pragma unroll
    for (int i = 0; i < 4; ++i)
        #pragma unroll
        for (int j = 0; j < 4; ++j) { acc[i][j].x = 0.f; acc[i][j].y = 0.f; acc[i][j].z = 0.f; acc[i][j].w = 0.f; }

    for (int k0 = 0; k0 < 1024; k0 += 32) {
        // A-stage: fp16 passthrough
        #pragma unroll
        for (int itr = 0; itr < 2; ++itr) {
            const int idx = itr * 256 + t;
            const int row = idx >> 2, kq = idx & 3;
            const uint4 p = *(const uint4*)(A + (long)row * 1024 + k0 + kq * 8);
            *(uint4*)&As[row * BKP + kq * 8] = p;
        }
        // B-stage: fp32 -> fp16
        #pragma unroll
        for (int itr = 0; itr < 2; ++itr) {
            const int idx = itr * 256 + t;
            const int row = idx >> 2, kq = idx & 3;
            const float* s = B + (long)(n0 + row) * 1024 + k0 + kq * 8;
            const float4 f0 = *(const float4*)s, f1 = *(const float4*)(s + 4);
            uint4 p;
            p.x = cvth2(f0.x, f0.y); p.y = cvth2(f0.z, f0.w);
            p.z = cvth2(f1.x, f1.y); p.w = cvth2(f1.z, f1.w);
            *(uint4*)&Bs[row * BKP + kq * 8] = p;
        }
        __syncthreads();

        f16x8 af[4], bfr[4];
        #pragma unroll
        for (int mi = 0; mi < 4; ++mi)
            af[mi] = *(const f16x8*)&As[(wr * 64 + mi * 16 + (lane & 15)) * BKP + (lane >> 4) * 8];
        #pragma unroll
        for (int ni = 0; ni < 4; ++ni)
            bfr[ni] = *(const f16x8*)&Bs[(wc * 64 + ni * 16 + (lane & 15)) * BKP + (lane >> 4) * 8];
        #pragma unroll
        for (int mi = 0; mi < 4; ++mi)
            #pragma unroll
            for (int ni = 0; ni < 4; ++ni)
                acc[mi][ni] = __builtin_amdgcn_mfma_f32_16x16x32_f16(af[mi], bfr[ni], acc[mi][ni], 0, 0, 0);
        __syncthreads();
    }

    // ---- column (over s) max: 10*acc ----
    float lm[4];
    #pragma unroll
    for (int ni = 0; ni < 4; ++ni) {
        float mx = -INFINITY;
        #pragma unroll
        for (int mi = 0; mi < 4; ++mi)
            #pragma unroll
            for (int j = 0; j < 4; ++j) mx = fmaxf(mx, acc[mi][ni][j]);
        mx *= 10.0f;
        mx = fmaxf(mx, __shfl_xor(mx, 16, 64));
        mx = fmaxf(mx, __shfl_xor(mx, 32, 64));
        lm[ni] = mx;
    }
    if ((lane >> 4) == 0) {
        #pragma unroll
        for (int ni = 0; ni < 4; ++ni) colmax[wr][wc * 64 + ni * 16 + lane] = lm[ni];
    }
    __syncthreads();
    float cm[4];
    #pragma unroll
    for (int ni = 0; ni < 4; ++ni) {
        const int c = wc * 64 + ni * 16 + (lane & 15);
        cm[ni] = fmaxf(colmax[0][c], colmax[1][c]);
    }
    if (wr == 0 && (lane >> 4) == 0) {
        #pragma unroll
        for (int ni = 0; ni < 4; ++ni)
            MiB[(long)zb * 1024 + n0 + wc * 64 + ni * 16 + lane] = cm[ni];
    }
    // ---- ek = bf16(exp(10*acc - cm)) ----
    unsigned short* ekz = ekb + (long)zb * (OUT_SIZE * IN_SIZE);
    #pragma unroll
    for (int mi = 0; mi < 4; ++mi) {
        #pragma unroll
        for (int ni = 0; ni < 4; ++ni) {
            const int col = n0 + wc * 64 + ni * 16 + (lane & 15);
            #pragma unroll
            for (int j = 0; j < 4; ++j) {
                const int row = wr * 64 + mi * 16 + (lane >> 4) * 4 + j;
                ekz[(long)row * 1024 + col] = bf16rne(__expf(fmaf(acc[mi][ni][j], 10.f, -cm[ni])));
            }
        }
    }
}

// ---------------------------------------------------------------------------
__global__ __launch_bounds__(256)
void transpose_cvt(const float* __restrict__ x, unsigned short* __restrict__ xT)
{
    const int n = blockIdx.z, i0 = blockIdx.y * 64, d0 = blockIdx.x * 64;
    const float* xs = x + (long)n * (IN_SIZE * IN_DIM);
    unsigned short* xo = xT + (long)n * (IN_SIZE * IN_DIM);
    __shared__ float tile[64][65];
    const int t = threadIdx.x;
    const int r = t >> 4, c4 = (t & 15) * 4;
    #pragma unroll
    for (int rr = 0; rr < 4; ++rr) {
        const float4 v = *(const float4*)(xs + (long)(i0 + rr * 16 + r) * IN_DIM + d0 + c4);
        *(float4*)&tile[rr * 16 + r][c4] = v;
    }
    __syncthreads();
    #pragma unroll
    for (int rr = 0; rr < 4; ++rr) {
        const int dl = rr * 16 + r;
        ushort4 o;
        o.x = cvth1(tile[c4 + 0][dl]); o.y = cvth1(tile[c4 + 1][dl]);
        o.z = cvth1(tile[c4 + 2][dl]); o.w = cvth1(tile[c4 + 3][dl]);
        *(ushort4*)(xo + (long)(d0 + dl) * IN_SIZE + i0 + c4) = o;
    }
}

// ---------------------------------------------------------------------------
// Sinkhorn v6: LDS-resident split-tile (as R10/R11) that WRITES T fp16
// directly over the dead ek region. T = ek * exp(w-wg) * exp(v+wg) with
// everything already in LDS/regs -> GEMM2 becomes a plain fp16 GEMM (its
// per-block A transform was re-executed 8x per tile and was ~half its
// staging VALU). euv side-channel eliminated.
// ---------------------------------------------------------------------------
__global__ __launch_bounds__(512)
void sinkhorn_split(unsigned short* __restrict__ ekb,
                    const float* __restrict__ MiB,
                    float* __restrict__ xchg, unsigned int* __restrict__ ctr)
{
    const int q = blockIdx.x;          // i-quarter 0..3
    const int b = blockIdx.z;          // tile 0..63
    const int t = threadIdx.x;
    const int lane = t & 63, w = t >> 6;

    __shared__ unsigned ekw[128 * 129];    // bf16-pairs, row stride 129 dw
    __shared__ float part_u[4][256];
    __shared__ float part_v[4][128];
    __shared__ float eu_l[256];
    __shared__ float v_s[128], ev_s[128];
    __shared__ float red8[8];
    __shared__ float wg_s;

    // ---- one-time ek load: [128 s][256 i-local] ----
    {
        const unsigned short* src = ekb + (long)b * 131072 + q * 256;
        #pragma unroll
        for (int j = 0; j < 8; ++j) {
            const int idx = t + 512 * j;          // 0..4095
            const int s = idx >> 5, c8 = (idx & 31) * 8;
            const uint4 p = *(const uint4*)(src + (long)s * 1024 + c8);
            const int bd = s * 129 + (c8 >> 1);
            ekw[bd] = p.x; ekw[bd + 1] = p.y; ekw[bd + 2] = p.z; ekw[bd + 3] = p.w;
        }
    }
    float mi_t = 0.f, u_reg = 0.f, w_t = 0.f;
    if (t < 256) mi_t = MiB[(long)b * 1024 + q * 256 + t];
    if (t < 128) v_s[t] = 0.f;
    __syncthreads();

    const float A0 = -2.0794415416798357f;  // log(128/1024)

    for (int it = 0; it < MAX_ITER; ++it) {
        // ---- vmx + ev (redundant in all blocks, identical) ----
        if (t < 128) {
            float xv = v_s[t];
            #pragma unroll
            for (int m = 1; m < 64; m <<= 1) xv = fmaxf(xv, __shfl_xor(xv, m, 64));
            if (lane == 0) red8[w] = xv;
        }
        __syncthreads();
        const float vmx = fmaxf(red8[0], red8[1]);
        if (t < 128) ev_s[t] = __expf(v_s[t] - vmx);
        __syncthreads();

        // ---- u-pass: local over all 128 s ----
        {
            const int p = t & 127, sq = t >> 7;
            float s0 = 0.f, s1 = 0.f;
            #pragma unroll
            for (int j = 0; j < 32; ++j) {
                const int s = sq * 32 + j;
                const unsigned e = ekw[s * 129 + p];
                const float evv = ev_s[s];
                s0 = fmaf(__uint_as_float(e << 16),          evv, s0);
                s1 = fmaf(__uint_as_float(e & 0xffff0000u),  evv, s1);
            }
            part_u[sq][2 * p]     = s0;
            part_u[sq][2 * p + 1] = s1;
        }
        __syncthreads();

        // ---- u update (t<256 owns i-local = t), local wmx ----
        if (t < 256) {
            const float S = part_u[0][t] + part_u[1][t] + part_u[2][t] + part_u[3][t];
            const float un = A0 - u_reg - mi_t - vmx - __logf(S);
            u_reg = un;
            w_t = mi_t + un;
            float wl = w_t;
            #pragma unroll
            for (int m = 1; m < 64; m <<= 1) wl = fmaxf(wl, __shfl_xor(wl, m, 64));
            if (lane == 0) red8[4 + w] = wl;
        }
        __syncthreads();
        const float wmx_l = fmaxf(fmaxf(red8[4], red8[5]), fmaxf(red8[6], red8[7]));
        if (t < 256) eu_l[t] = __expf(w_t - wmx_l);
        __syncthreads();

        // ---- v-pass: local partial column sums ----
        {
            const int s = t & 127, g = t >> 7;
            float acc = 0.f;
            #pragma unroll
            for (int j = 0; j < 32; ++j) {
                const int p = 32 * g + j;
                const unsigned e = ekw[s * 129 + p];
                const float2 eup = *(const float2*)&eu_l[2 * p];
                acc = fmaf(__uint_as_float(e << 16),         eup.x, acc);
                acc = fmaf(__uint_as_float(e & 0xffff0000u), eup.y, acc);
            }
            part_v[g][s] = acc;
        }
        __syncthreads();

        // ---- publish (cp_local, wmx_l), arrive, wait ----
        float* slot = xchg + ((long)(b * MAX_ITER + it) * 4 + q) * 160;
        if (t < 128) {
            const float cp_l = part_v[0][t] + part_v[1][t] + part_v[2][t] + part_v[3][t];
            __hip_atomic_store(slot + t, cp_l, __ATOMIC_RELAXED, __HIP_MEMORY_SCOPE_AGENT);
        }
        if (t == 0)
            __hip_atomic_store(slot + 128, wmx_l, __ATOMIC_RELAXED, __HIP_MEMORY_SCOPE_AGENT);
        __syncthreads();
        if (t == 0) {
            unsigned int* c = ctr + b * MAX_ITER + it;
            __hip_atomic_fetch_add(c, 1u, __ATOMIC_RELEASE, __HIP_MEMORY_SCOPE_AGENT);
            while (__hip_atomic_load(c, __ATOMIC_ACQUIRE, __HIP_MEMORY_SCOPE_AGENT) < 4u)
                __builtin_amdgcn_s_sleep(1);
        }
        __syncthreads();

        // ---- combine (identical in all 4 blocks) ----
        if (t < 128) {
            float* base = xchg + (long)(b * MAX_ITER + it) * 4 * 160;
            const float w0 = __hip_atomic_load(base + 0 * 160 + 128, __ATOMIC_RELAXED, __HIP_MEMORY_SCOPE_AGENT);
            const float w1 = __hip_atomic_load(base + 1 * 160 + 128, __ATOMIC_RELAXED, __HIP_MEMORY_SCOPE_AGENT);
            const float w2 = __hip_atomic_load(base + 2 * 160 + 128, __ATOMIC_RELAXED, __HIP_MEMORY_SCOPE_AGENT);
            const float w3 = __hip_atomic_load(base + 3 * 160 + 128, __ATOMIC_RELAXED, __HIP_MEMORY_SCOPE_AGENT);
            const float wg = fmaxf(fmaxf(w0, w1), fmaxf(w2, w3));
            const float c0 = __hip_atomic_load(base + 0 * 160 + t, __ATOMIC_RELAXED, __HIP_MEMORY_SCOPE_AGENT);
            const float c1 = __hip_atomic_load(base + 1 * 160 + t, __ATOMIC_RELAXED, __HIP_MEMORY_SCOPE_AGENT);
            const float c2 = __hip_atomic_load(base + 2 * 160 + t, __ATOMIC_RELAXED, __HIP_MEMORY_SCOPE_AGENT);
            const float c3 = __hip_atomic_load(base + 3 * 160 + t, __ATOMIC_RELAXED, __HIP_MEMORY_SCOPE_AGENT);
            const float cp = c0 * __expf(w0 - wg) + c1 * __expf(w1 - wg)
                           + c2 * __expf(w2 - wg) + c3 * __expf(w3 - wg);
            v_s[t] = -v_s[t] - wg - __logf(cp);
            if (t == 0) wg_s = wg;
        }
        __syncthreads();
    }

    // ---- write T fp16 over own ek slice: T = ek * eu[i] * ecv[s] ----
    const float wg = wg_s;
    if (t < 256) eu_l[t] = __expf(w_t - wg);          // global-normalized eu
    if (t < 128) ev_s[t] = __expf(v_s[t] + wg);       // ecv
    __syncthreads();
    unsigned short* To = ekb + (long)b * 131072 + q * 256;
    #pragma unroll
    for (int j = 0; j < 32; ++j) {
        const int idx = t + 512 * j;          // 0..16383
        const int s  = idx >> 7;              // 0..127
        const int ip = idx & 127;             // bf16-pair index 0..127
        const unsigned e = ekw[s * 129 + ip];
        const float2 eup = *(const float2*)&eu_l[2 * ip];
        const float ec = ev_s[s];
        const float lo = __uint_as_float(e << 16)         * eup.x * ec;
        const float hi = __uint_as_float(e & 0xffff0000u) * eup.y * ec;
        *(unsigned*)(To + (long)s * 1024 + ip * 2) = cvth2(lo, hi);
    }
}

// ---------------------------------------------------------------------------
extern "C" void kernel_launch(void* const* d_in, const int* in_sizes, int n_in,
                              void* d_out, int out_size, void* d_ws, size_t ws_size,
                              hipStream_t stream)
{
    const float* x     = (const float*)d_in[0];   // [16][1024][1024]
    const float* otw   = (const float*)d_in[1];   // [4][128][1024]
    const float* lin_w = (const float*)d_in[2];   // [1024][4096]
    const float* lin_b = (const float*)d_in[3];   // [1024]
    float* out = (float*)d_out;                   // [16][128][1024] fp32 (8 MB)

    // ws (64 MB): [0,32M) xT fp16 (dead after GEMM2 -> split-K partials)
    //             [32M,48M) ek bf16 -> overwritten in-place with T fp16
    //             [48M,64M) feat fp16
    unsigned short* xT   = (unsigned short*)d_ws;
    unsigned short* ekb  = xT + 16777216;         // ek, then T (same bytes)
    unsigned short* feat = ekb + 8388608;
    float* partial = (float*)d_ws;                // [4][16][128][1024] f32
    // d_out scratch (fully overwritten by splitk_reduce):
    //   Mi [64][1024] @0 ; xchg [64][10][4][160] @131072 ; ctr @655360 ;
    //   otwH fp16 [512][1024] @786432 (floats)
    float* MiB  = (float*)d_out;
    float* xchg = MiB + 131072;
    unsigned int* ctrB = (unsigned int*)(MiB + 655360);
    unsigned short* otwH = (unsigned short*)(MiB + 786432);

    // reset arrival counters (stream-ordered, capture-legal)
    hipMemsetAsync(ctrB, 0, 64 * MAX_ITER * sizeof(unsigned int), stream);

    // -1) otw fp32 -> fp16 (one-time, 2 MB -> 1 MB)
    cvt_otw<<<dim3(256), 256, 0, stream>>>(otw, otwH);

    // 0) x -> xT fp16
    transpose_cvt<<<dim3(16, 16, NB), 256, 0, stream>>>(x, xT);

    // 1) fused K-GEMM + colmax + exp -> ek bf16, Mi (R10 tiling)
    gemm1_exp<<<dim3(64, 1, 8), 256, 0, stream>>>(otwH, x, ekb, MiB);

    // 2) Sinkhorn: LDS-resident slices + handshake; writes T fp16 over ek
    sinkhorn_split<<<dim3(4, 1, 64), 512, 0, stream>>>(ekb, MiB, xchg, ctrB);

    // 3) feat[b][s][d] = sum_i T[s][i] * xT[n][d][i]  (plain fp16 GEMM,
    //    R10 tiling NF=4 grid (64,1,8), XCD-aligned)
    mfma_gemm<0, false, 1, 4, false, true><<<dim3(64, 1, 8), 256, 0, stream>>>(
        ekb, xT, nullptr, feat,
        1024, 1024, 1024, 1024, 4,
        524288, 131072, 1048576, 0, 524288, 131072, 0, 1.0f);

    // 4) split-K x4 GEMM3: partial[ks][n][s][o]
    mfma_gemm<0, true, 4, 2, false, false><<<dim3(16, 1, 64), 256, 0, stream>>>(
        feat, lin_w, nullptr, partial,
        1024, 1024, 4096, 1024, 16,
        131072, 524288, 1024, 0, 2097152, 131072, 0, 1.0f);

    // 5) out = relu(sum_ks partial + bias)
    splitk_reduce<<<dim3(2048), 256, 0, stream>>>(partial, lin_b, out);
}

// Round 14
// 210.812 us; speedup vs baseline: 1.0902x; 1.0587x over previous
//
#include <hip/hip_runtime.h>
#include <math.h>

#define EPSV 0.1f
#define MAX_ITER 10
constexpr int NB       = 16;
constexpr int IN_SIZE  = 1024;
constexpr int IN_DIM   = 1024;
constexpr int HEADS    = 4;
constexpr int OUT_SIZE = 128;
constexpr int OUT_DIM  = 1024;

typedef __attribute__((ext_vector_type(8))) _Float16 f16x8;
typedef __attribute__((ext_vector_type(4))) float f32x4;

__device__ __forceinline__ unsigned cvth2(float lo, float hi) {
    _Float16 a = (_Float16)lo, b = (_Float16)hi;
    unsigned short ua = *(unsigned short*)&a, ub = *(unsigned short*)&b;
    return (unsigned)ua | ((unsigned)ub << 16);
}
__device__ __forceinline__ unsigned short cvth1(float f) {
    _Float16 a = (_Float16)f;
    return *(unsigned short*)&a;
}
__device__ __forceinline__ unsigned short bf16rne(float f) {
    unsigned a = __float_as_uint(f);
    return (unsigned short)((a + 0x7fffu + ((a >> 16) & 1u)) >> 16);
}

// ---------------------------------------------------------------------------
// MFMA fp16 GEMM, M fixed at 128. C = alpha*A*B^T (+variants).
// AMODE: 0 = A fp16 passthrough
// B_F32: B fp32 -> fp16 in-flight, else fp16 passthrough
// CMODE: 1 = fp16 store, 2 = f32 + bias + relu, 4 = f32 raw (split-K partial)
// SWAP : batch index from blockIdx.x (XCD-aligned), n0 from blockIdx.z.
// ---------------------------------------------------------------------------
template<int AMODE, bool B_F32, int CMODE, int NF, bool AKBLK, bool SWAP>
__global__ __launch_bounds__(256)
void mfma_gemm(const void* __restrict__ Ap, const void* __restrict__ Bp,
               const float* __restrict__ bias, void* __restrict__ Cp,
               int K, int lda, int ldb, int ldc, int div,
               long AsN, long AsM, long BsN, long BsM, long CsN, long CsM,
               long AkStride, float alpha)
{
    constexpr int BN  = NF * 32;
    constexpr int BKP = 40;
    const int z  = SWAP ? blockIdx.x : blockIdx.z;
    const int n0 = (SWAP ? blockIdx.z : blockIdx.x) * BN;
    const long aoff = (long)(z / div) * AsN + (long)(z % div) * AsM;
    const long boff = (long)(z / div) * BsN + (long)(z % div) * BsM;
    const long coff = (long)(z / div) * CsN + (long)(z % div) * CsM;

    __shared__ short As[128 * BKP];
    __shared__ short Bs[BN * BKP];

    const int t = threadIdx.x;
    const int lane = t & 63;
    const int w = t >> 6, wr = w >> 1, wc = w & 1;

    f32x4 acc[4][NF];
    #pragma unroll
    for (int i = 0; i < 4; ++i)
        #pragma unroll
        for (int j = 0; j < NF; ++j) { acc[i][j].x = 0.f; acc[i][j].y = 0.f; acc[i][j].z = 0.f; acc[i][j].w = 0.f; }

    for (int k0 = 0; k0 < K; k0 += 32) {
        const long abase = AKBLK ? aoff + (long)(k0 >> 10) * AkStride + (k0 & 1023)
                                 : aoff + k0;
        const long bbase = boff + k0;
        // ---- stage A (128 x 32, fp16 passthrough) ----
        #pragma unroll
        for (int itr = 0; itr < 2; ++itr) {
            const int idx = itr * 256 + t;
            const int row = idx >> 2, kq = idx & 3;
            const uint4 p = *(const uint4*)((const short*)Ap + abase + (long)row * lda + kq * 8);
            *(uint4*)&As[row * BKP + kq * 8] = p;
        }
        // ---- stage B (BN x 32) ----
        #pragma unroll
        for (int itr = 0; itr < BN / 64; ++itr) {
            const int idx = itr * 256 + t;
            const int row = idx >> 2, kq = idx & 3;
            uint4 p;
            if (B_F32) {
                const float* s = (const float*)Bp + bbase + (long)(n0 + row) * ldb + kq * 8;
                const float4 f0 = *(const float4*)s, f1 = *(const float4*)(s + 4);
                p.x = cvth2(f0.x, f0.y); p.y = cvth2(f0.z, f0.w);
                p.z = cvth2(f1.x, f1.y); p.w = cvth2(f1.z, f1.w);
            } else {
                p = *(const uint4*)((const short*)Bp + bbase + (long)(n0 + row) * ldb + kq * 8);
            }
            *(uint4*)&Bs[row * BKP + kq * 8] = p;
        }
        __syncthreads();

        f16x8 af[4], bfr[NF];
        #pragma unroll
        for (int mi = 0; mi < 4; ++mi)
            af[mi] = *(const f16x8*)&As[(wr * 64 + mi * 16 + (lane & 15)) * BKP + (lane >> 4) * 8];
        #pragma unroll
        for (int ni = 0; ni < NF; ++ni)
            bfr[ni] = *(const f16x8*)&Bs[(wc * (BN / 2) + ni * 16 + (lane & 15)) * BKP + (lane >> 4) * 8];
        #pragma unroll
        for (int mi = 0; mi < 4; ++mi)
            #pragma unroll
            for (int ni = 0; ni < NF; ++ni)
                acc[mi][ni] = __builtin_amdgcn_mfma_f32_16x16x32_f16(af[mi], bfr[ni], acc[mi][ni], 0, 0, 0);
        __syncthreads();
    }

    #pragma unroll
    for (int mi = 0; mi < 4; ++mi) {
        #pragma unroll
        for (int ni = 0; ni < NF; ++ni) {
            #pragma unroll
            for (int j = 0; j < 4; ++j) {
                const int row = wr * 64 + mi * 16 + (lane >> 4) * 4 + j;
                const int col = n0 + wc * (BN / 2) + ni * 16 + (lane & 15);
                float v = acc[mi][ni][j] * alpha;
                if (CMODE == 2) { v += bias[col]; v = fmaxf(v, 0.f); }
                if (CMODE == 2 || CMODE == 4) ((float*)Cp)[coff + (long)row * ldc + col] = v;
                else ((unsigned short*)Cp)[coff + (long)row * ldc + col] = cvth1(v);
            }
        }
    }
}

// ---------------------------------------------------------------------------
__global__ __launch_bounds__(256)
void splitk_reduce(const float* __restrict__ part, const float* __restrict__ bias,
                   float* __restrict__ out)
{
    const long idx = ((long)blockIdx.x * 256 + threadIdx.x) * 4;
    const int o = (int)(idx & 1023);
    const float4 p0 = *(const float4*)(part + idx);
    const float4 p1 = *(const float4*)(part + 2097152 + idx);
    const float4 p2 = *(const float4*)(part + 2 * 2097152 + idx);
    const float4 p3 = *(const float4*)(part + 3 * 2097152 + idx);
    const float4 bv = *(const float4*)(bias + o);
    float4 r;
    r.x = fmaxf(p0.x + p1.x + p2.x + p3.x + bv.x, 0.f);
    r.y = fmaxf(p0.y + p1.y + p2.y + p3.y + bv.y, 0.f);
    r.z = fmaxf(p0.z + p1.z + p2.z + p3.z + bv.z, 0.f);
    r.w = fmaxf(p0.w + p1.w + p2.w + p3.w + bv.w, 0.f);
    *(float4*)(out + idx) = r;
}

// ---------------------------------------------------------------------------
__global__ __launch_bounds__(256)
void cvt_otw(const float* __restrict__ in, unsigned short* __restrict__ out)
{
    const long i8 = ((long)blockIdx.x * 256 + threadIdx.x) * 8;
    const float4 f0 = *(const float4*)(in + i8), f1 = *(const float4*)(in + i8 + 4);
    uint4 p;
    p.x = cvth2(f0.x, f0.y); p.y = cvth2(f0.z, f0.w);
    p.z = cvth2(f1.x, f1.y); p.w = cvth2(f1.z, f1.w);
    *(uint4*)(out + i8) = p;
}

// ---------------------------------------------------------------------------
// GEMM1 fused (R10 tiling: BN=128, grid (64,1,8), 2 blocks/CU), fp16 A.
// XCD-aligned: tile = blockIdx.x -> all of tile b's ek on XCD b%8.
// ---------------------------------------------------------------------------
__global__ __launch_bounds__(256)
void gemm1_exp(const unsigned short* __restrict__ otwH, const float* __restrict__ x,
               unsigned short* __restrict__ ekb, float* __restrict__ MiB)
{
    constexpr int BKP = 40;
    const int zb = blockIdx.x;                // b = n*4+m  (XCD-aligned)
    const int nn = zb >> 2, mm = zb & 3;
    const unsigned short* A = otwH + (long)mm * (OUT_SIZE * IN_DIM);  // [128][1024] fp16
    const float* B = x + (long)nn * (IN_SIZE * IN_DIM);               // [1024][1024] fp32
    const int n0 = blockIdx.z * 128;          // i-chunk

    __shared__ short As[128 * BKP];
    __shared__ short Bs[128 * BKP];
    __shared__ float colmax[2][128];

    const int t = threadIdx.x;
    const int lane = t & 63;
    const int w = t >> 6, wr = w >> 1, wc = w & 1;

    f32x4 acc[4][4];
    #pragma unroll
    for (int i = 0; i < 4; ++i)
        #pragma unroll
        for (int j = 0; j < 4; ++j) { acc[i][j].x = 0.f; acc[i][j].y = 0.f; acc[i][j].z = 0.f; acc[i][j].w = 0.f; }

    for (int k0 = 0; k0 < 1024; k0 += 32) {
        #pragma unroll
        for (int itr = 0; itr < 2; ++itr) {
            const int idx = itr * 256 + t;
            const int row = idx >> 2, kq = idx & 3;
            const uint4 p = *(const uint4*)(A + (long)row * 1024 + k0 + kq * 8);
            *(uint4*)&As[row * BKP + kq * 8] = p;
        }
        #pragma unroll
        for (int itr = 0; itr < 2; ++itr) {
            const int idx = itr * 256 + t;
            const int row = idx >> 2, kq = idx & 3;
            const float* s = B + (long)(n0 + row) * 1024 + k0 + kq * 8;
            const float4 f0 = *(const float4*)s, f1 = *(const float4*)(s + 4);
            uint4 p;
            p.x = cvth2(f0.x, f0.y); p.y = cvth2(f0.z, f0.w);
            p.z = cvth2(f1.x, f1.y); p.w = cvth2(f1.z, f1.w);
            *(uint4*)&Bs[row * BKP + kq * 8] = p;
        }
        __syncthreads();

        f16x8 af[4], bfr[4];
        #pragma unroll
        for (int mi = 0; mi < 4; ++mi)
            af[mi] = *(const f16x8*)&As[(wr * 64 + mi * 16 + (lane & 15)) * BKP + (lane >> 4) * 8];
        #pragma unroll
        for (int ni = 0; ni < 4; ++ni)
            bfr[ni] = *(const f16x8*)&Bs[(wc * 64 + ni * 16 + (lane & 15)) * BKP + (lane >> 4) * 8];
        #pragma unroll
        for (int mi = 0; mi < 4; ++mi)
            #pragma unroll
            for (int ni = 0; ni < 4; ++ni)
                acc[mi][ni] = __builtin_amdgcn_mfma_f32_16x16x32_f16(af[mi], bfr[ni], acc[mi][ni], 0, 0, 0);
        __syncthreads();
    }

    float lm[4];
    #pragma unroll
    for (int ni = 0; ni < 4; ++ni) {
        float mx = -INFINITY;
        #pragma unroll
        for (int mi = 0; mi < 4; ++mi)
            #pragma unroll
            for (int j = 0; j < 4; ++j) mx = fmaxf(mx, acc[mi][ni][j]);
        mx *= 10.0f;
        mx = fmaxf(mx, __shfl_xor(mx, 16, 64));
        mx = fmaxf(mx, __shfl_xor(mx, 32, 64));
        lm[ni] = mx;
    }
    if ((lane >> 4) == 0) {
        #pragma unroll
        for (int ni = 0; ni < 4; ++ni) colmax[wr][wc * 64 + ni * 16 + lane] = lm[ni];
    }
    __syncthreads();
    float cm[4];
    #pragma unroll
    for (int ni = 0; ni < 4; ++ni) {
        const int c = wc * 64 + ni * 16 + (lane & 15);
        cm[ni] = fmaxf(colmax[0][c], colmax[1][c]);
    }
    if (wr == 0 && (lane >> 4) == 0) {
        #pragma unroll
        for (int ni = 0; ni < 4; ++ni)
            MiB[(long)zb * 1024 + n0 + wc * 64 + ni * 16 + lane] = cm[ni];
    }
    unsigned short* ekz = ekb + (long)zb * (OUT_SIZE * IN_SIZE);
    #pragma unroll
    for (int mi = 0; mi < 4; ++mi) {
        #pragma unroll
        for (int ni = 0; ni < 4; ++ni) {
            const int col = n0 + wc * 64 + ni * 16 + (lane & 15);
            #pragma unroll
            for (int j = 0; j < 4; ++j) {
                const int row = wr * 64 + mi * 16 + (lane >> 4) * 4 + j;
                ekz[(long)row * 1024 + col] = bf16rne(__expf(fmaf(acc[mi][ni][j], 10.f, -cm[ni])));
            }
        }
    }
}

// ---------------------------------------------------------------------------
__global__ __launch_bounds__(256)
void transpose_cvt(const float* __restrict__ x, unsigned short* __restrict__ xT)
{
    const int n = blockIdx.z, i0 = blockIdx.y * 64, d0 = blockIdx.x * 64;
    const float* xs = x + (long)n * (IN_SIZE * IN_DIM);
    unsigned short* xo = xT + (long)n * (IN_SIZE * IN_DIM);
    __shared__ float tile[64][65];
    const int t = threadIdx.x;
    const int r = t >> 4, c4 = (t & 15) * 4;
    #pragma unroll
    for (int rr = 0; rr < 4; ++rr) {
        const float4 v = *(const float4*)(xs + (long)(i0 + rr * 16 + r) * IN_DIM + d0 + c4);
        *(float4*)&tile[rr * 16 + r][c4] = v;
    }
    __syncthreads();
    #pragma unroll
    for (int rr = 0; rr < 4; ++rr) {
        const int dl = rr * 16 + r;
        ushort4 o;
        o.x = cvth1(tile[c4 + 0][dl]); o.y = cvth1(tile[c4 + 1][dl]);
        o.z = cvth1(tile[c4 + 2][dl]); o.w = cvth1(tile[c4 + 3][dl]);
        *(ushort4*)(xo + (long)(d0 + dl) * IN_SIZE + i0 + c4) = o;
    }
}

// ---------------------------------------------------------------------------
// Sinkhorn v6.1: LDS-resident split-tile, SIBLINGS CO-LOCATED ON ONE XCD.
// Grid (64,1,4): b = blockIdx.x, q = blockIdx.z -> linear id = b + 64q ==
// b (mod 8) -> all 4 siblings of tile b on XCD b%8, SAME XCD where gemm1
// wrote ek tile b and where GEMM2 block b reads T. The per-iteration
// handshake (R12: 4 siblings on 4 different XCDs -> every publish/poll
// crossed XCDs through L3) is now serviced by the local L2. Atomics stay
// agent-scope: placement affects only speed, never correctness (G16).
// ---------------------------------------------------------------------------
__global__ __launch_bounds__(512)
void sinkhorn_split(unsigned short* __restrict__ ekb,
                    const float* __restrict__ MiB,
                    float* __restrict__ xchg, unsigned int* __restrict__ ctr)
{
    const int b = blockIdx.x;          // tile 0..63 (XCD-aligned)
    const int q = blockIdx.z;          // i-quarter 0..3
    const int t = threadIdx.x;
    const int lane = t & 63, w = t >> 6;

    __shared__ unsigned ekw[128 * 129];    // bf16-pairs, row stride 129 dw
    __shared__ float part_u[4][256];
    __shared__ float part_v[4][128];
    __shared__ float eu_l[256];
    __shared__ float v_s[128], ev_s[128];
    __shared__ float red8[8];
    __shared__ float wg_s;

    // ---- one-time ek load: [128 s][256 i-local] ----
    {
        const unsigned short* src = ekb + (long)b * 131072 + q * 256;
        #pragma unroll
        for (int j = 0; j < 8; ++j) {
            const int idx = t + 512 * j;          // 0..4095
            const int s = idx >> 5, c8 = (idx & 31) * 8;
            const uint4 p = *(const uint4*)(src + (long)s * 1024 + c8);
            const int bd = s * 129 + (c8 >> 1);
            ekw[bd] = p.x; ekw[bd + 1] = p.y; ekw[bd + 2] = p.z; ekw[bd + 3] = p.w;
        }
    }
    float mi_t = 0.f, u_reg = 0.f, w_t = 0.f;
    if (t < 256) mi_t = MiB[(long)b * 1024 + q * 256 + t];
    if (t < 128) v_s[t] = 0.f;
    __syncthreads();

    const float A0 = -2.0794415416798357f;  // log(128/1024)

    for (int it = 0; it < MAX_ITER; ++it) {
        // ---- vmx + ev (redundant in all blocks, identical) ----
        if (t < 128) {
            float xv = v_s[t];
            #pragma unroll
            for (int m = 1; m < 64; m <<= 1) xv = fmaxf(xv, __shfl_xor(xv, m, 64));
            if (lane == 0) red8[w] = xv;
        }
        __syncthreads();
        const float vmx = fmaxf(red8[0], red8[1]);
        if (t < 128) ev_s[t] = __expf(v_s[t] - vmx);
        __syncthreads();

        // ---- u-pass: local over all 128 s ----
        {
            const int p = t & 127, sq = t >> 7;
            float s0 = 0.f, s1 = 0.f;
            #pragma unroll
            for (int j = 0; j < 32; ++j) {
                const int s = sq * 32 + j;
                const unsigned e = ekw[s * 129 + p];
                const float evv = ev_s[s];
                s0 = fmaf(__uint_as_float(e << 16),          evv, s0);
                s1 = fmaf(__uint_as_float(e & 0xffff0000u),  evv, s1);
            }
            part_u[sq][2 * p]     = s0;
            part_u[sq][2 * p + 1] = s1;
        }
        __syncthreads();

        // ---- u update (t<256 owns i-local = t), local wmx ----
        if (t < 256) {
            const float S = part_u[0][t] + part_u[1][t] + part_u[2][t] + part_u[3][t];
            const float un = A0 - u_reg - mi_t - vmx - __logf(S);
            u_reg = un;
            w_t = mi_t + un;
            float wl = w_t;
            #pragma unroll
            for (int m = 1; m < 64; m <<= 1) wl = fmaxf(wl, __shfl_xor(wl, m, 64));
            if (lane == 0) red8[4 + w] = wl;
        }
        __syncthreads();
        const float wmx_l = fmaxf(fmaxf(red8[4], red8[5]), fmaxf(red8[6], red8[7]));
        if (t < 256) eu_l[t] = __expf(w_t - wmx_l);
        __syncthreads();

        // ---- v-pass: local partial column sums ----
        {
            const int s = t & 127, g = t >> 7;
            float acc = 0.f;
            #pragma unroll
            for (int j = 0; j < 32; ++j) {
                const int p = 32 * g + j;
                const unsigned e = ekw[s * 129 + p];
                const float2 eup = *(const float2*)&eu_l[2 * p];
                acc = fmaf(__uint_as_float(e << 16),         eup.x, acc);
                acc = fmaf(__uint_as_float(e & 0xffff0000u), eup.y, acc);
            }
            part_v[g][s] = acc;
        }
        __syncthreads();

        // ---- publish (cp_local, wmx_l), arrive, wait ----
        float* slot = xchg + ((long)(b * MAX_ITER + it) * 4 + q) * 160;
        if (t < 128) {
            const float cp_l = part_v[0][t] + part_v[1][t] + part_v[2][t] + part_v[3][t];
            __hip_atomic_store(slot + t, cp_l, __ATOMIC_RELAXED, __HIP_MEMORY_SCOPE_AGENT);
        }
        if (t == 0)
            __hip_atomic_store(slot + 128, wmx_l, __ATOMIC_RELAXED, __HIP_MEMORY_SCOPE_AGENT);
        __syncthreads();
        if (t == 0) {
            unsigned int* c = ctr + b * MAX_ITER + it;
            __hip_atomic_fetch_add(c, 1u, __ATOMIC_RELEASE, __HIP_MEMORY_SCOPE_AGENT);
            while (__hip_atomic_load(c, __ATOMIC_ACQUIRE, __HIP_MEMORY_SCOPE_AGENT) < 4u)
                __builtin_amdgcn_s_sleep(1);
        }
        __syncthreads();

        // ---- combine (identical in all 4 blocks) ----
        if (t < 128) {
            float* base = xchg + (long)(b * MAX_ITER + it) * 4 * 160;
            const float w0 = __hip_atomic_load(base + 0 * 160 + 128, __ATOMIC_RELAXED, __HIP_MEMORY_SCOPE_AGENT);
            const float w1 = __hip_atomic_load(base + 1 * 160 + 128, __ATOMIC_RELAXED, __HIP_MEMORY_SCOPE_AGENT);
            const float w2 = __hip_atomic_load(base + 2 * 160 + 128, __ATOMIC_RELAXED, __HIP_MEMORY_SCOPE_AGENT);
            const float w3 = __hip_atomic_load(base + 3 * 160 + 128, __ATOMIC_RELAXED, __HIP_MEMORY_SCOPE_AGENT);
            const float wg = fmaxf(fmaxf(w0, w1), fmaxf(w2, w3));
            const float c0 = __hip_atomic_load(base + 0 * 160 + t, __ATOMIC_RELAXED, __HIP_MEMORY_SCOPE_AGENT);
            const float c1 = __hip_atomic_load(base + 1 * 160 + t, __ATOMIC_RELAXED, __HIP_MEMORY_SCOPE_AGENT);
            const float c2 = __hip_atomic_load(base + 2 * 160 + t, __ATOMIC_RELAXED, __HIP_MEMORY_SCOPE_AGENT);
            const float c3 = __hip_atomic_load(base + 3 * 160 + t, __ATOMIC_RELAXED, __HIP_MEMORY_SCOPE_AGENT);
            const float cp = c0 * __expf(w0 - wg) + c1 * __expf(w1 - wg)
                           + c2 * __expf(w2 - wg) + c3 * __expf(w3 - wg);
            v_s[t] = -v_s[t] - wg - __logf(cp);
            if (t == 0) wg_s = wg;
        }
        __syncthreads();
    }

    // ---- write T fp16 over own ek slice: T = ek * eu[i] * ecv[s] ----
    const float wg = wg_s;
    if (t < 256) eu_l[t] = __expf(w_t - wg);          // global-normalized eu
    if (t < 128) ev_s[t] = __expf(v_s[t] + wg);       // ecv
    __syncthreads();
    unsigned short* To = ekb + (long)b * 131072 + q * 256;
    #pragma unroll
    for (int j = 0; j < 32; ++j) {
        const int idx = t + 512 * j;          // 0..16383
        const int s  = idx >> 7;              // 0..127
        const int ip = idx & 127;             // bf16-pair index 0..127
        const unsigned e = ekw[s * 129 + ip];
        const float2 eup = *(const float2*)&eu_l[2 * ip];
        const float ec = ev_s[s];
        const float lo = __uint_as_float(e << 16)         * eup.x * ec;
        const float hi = __uint_as_float(e & 0xffff0000u) * eup.y * ec;
        *(unsigned*)(To + (long)s * 1024 + ip * 2) = cvth2(lo, hi);
    }
}

// ---------------------------------------------------------------------------
extern "C" void kernel_launch(void* const* d_in, const int* in_sizes, int n_in,
                              void* d_out, int out_size, void* d_ws, size_t ws_size,
                              hipStream_t stream)
{
    const float* x     = (const float*)d_in[0];   // [16][1024][1024]
    const float* otw   = (const float*)d_in[1];   // [4][128][1024]
    const float* lin_w = (const float*)d_in[2];   // [1024][4096]
    const float* lin_b = (const float*)d_in[3];   // [1024]
    float* out = (float*)d_out;                   // [16][128][1024] fp32 (8 MB)

    // ws (64 MB): [0,32M) xT fp16 (dead after GEMM2 -> split-K partials)
    //             [32M,48M) ek bf16 -> overwritten in-place with T fp16
    //             [48M,64M) feat fp16
    unsigned short* xT   = (unsigned short*)d_ws;
    unsigned short* ekb  = xT + 16777216;         // ek, then T (same bytes)
    unsigned short* feat = ekb + 8388608;
    float* partial = (float*)d_ws;                // [4][16][128][1024] f32
    // d_out scratch (fully overwritten by splitk_reduce):
    //   Mi [64][1024] @0 ; xchg [64][10][4][160] @131072 ; ctr @655360 ;
    //   otwH fp16 [512][1024] @786432 (floats)
    float* MiB  = (float*)d_out;
    float* xchg = MiB + 131072;
    unsigned int* ctrB = (unsigned int*)(MiB + 655360);
    unsigned short* otwH = (unsigned short*)(MiB + 786432);

    // reset arrival counters (stream-ordered, capture-legal)
    hipMemsetAsync(ctrB, 0, 64 * MAX_ITER * sizeof(unsigned int), stream);

    // -1) otw fp32 -> fp16 (one-time, 2 MB -> 1 MB)
    cvt_otw<<<dim3(256), 256, 0, stream>>>(otw, otwH);

    // 0) x -> xT fp16
    transpose_cvt<<<dim3(16, 16, NB), 256, 0, stream>>>(x, xT);

    // 1) fused K-GEMM + colmax + exp -> ek bf16, Mi (R10 tiling)
    gemm1_exp<<<dim3(64, 1, 8), 256, 0, stream>>>(otwH, x, ekb, MiB);

    // 2) Sinkhorn: siblings co-located per tile on one XCD (grid 64x1x4)
    sinkhorn_split<<<dim3(64, 1, 4), 512, 0, stream>>>(ekb, MiB, xchg, ctrB);

    // 3) feat[b][s][d] = sum_i T[s][i] * xT[n][d][i]  (plain fp16 GEMM,
    //    NF=4 grid (64,1,8), XCD-aligned)
    mfma_gemm<0, false, 1, 4, false, true><<<dim3(64, 1, 8), 256, 0, stream>>>(
        ekb, xT, nullptr, feat,
        1024, 1024, 1024, 1024, 4,
        524288, 131072, 1048576, 0, 524288, 131072, 0, 1.0f);

    // 4) split-K x4 GEMM3: partial[ks][n][s][o]
    mfma_gemm<0, true, 4, 2, false, false><<<dim3(16, 1, 64), 256, 0, stream>>>(
        feat, lin_w, nullptr, partial,
        1024, 1024, 4096, 1024, 16,
        131072, 524288, 1024, 0, 2097152, 131072, 0, 1.0f);

    // 5) out = relu(sum_ks partial + bias)
    splitk_reduce<<<dim3(2048), 256, 0, stream>>>(partial, lin_b, out);
}

// Round 15
// 210.274 us; speedup vs baseline: 1.0930x; 1.0026x over previous
//
#include <hip/hip_runtime.h>
#include <math.h>

#define EPSV 0.1f
#define MAX_ITER 10
constexpr int NB       = 16;
constexpr int IN_SIZE  = 1024;
constexpr int IN_DIM   = 1024;
constexpr int HEADS    = 4;
constexpr int OUT_SIZE = 128;
constexpr int OUT_DIM  = 1024;

typedef __attribute__((ext_vector_type(8))) _Float16 f16x8;
typedef __attribute__((ext_vector_type(4))) float f32x4;

__device__ __forceinline__ unsigned cvth2(float lo, float hi) {
    _Float16 a = (_Float16)lo, b = (_Float16)hi;
    unsigned short ua = *(unsigned short*)&a, ub = *(unsigned short*)&b;
    return (unsigned)ua | ((unsigned)ub << 16);
}
__device__ __forceinline__ unsigned short cvth1(float f) {
    _Float16 a = (_Float16)f;
    return *(unsigned short*)&a;
}
__device__ __forceinline__ unsigned short bf16rne(float f) {
    unsigned a = __float_as_uint(f);
    return (unsigned short)((a + 0x7fffu + ((a >> 16) & 1u)) >> 16);
}

// ---------------------------------------------------------------------------
// MFMA fp16 GEMM, M fixed at 128. C = alpha*A*B^T (+variants). (unchanged)
// ---------------------------------------------------------------------------
template<int AMODE, bool B_F32, int CMODE, int NF, bool AKBLK, bool SWAP>
__global__ __launch_bounds__(256)
void mfma_gemm(const void* __restrict__ Ap, const void* __restrict__ Bp,
               const float* __restrict__ bias, void* __restrict__ Cp,
               int K, int lda, int ldb, int ldc, int div,
               long AsN, long AsM, long BsN, long BsM, long CsN, long CsM,
               long AkStride, float alpha)
{
    constexpr int BN  = NF * 32;
    constexpr int BKP = 40;
    const int z  = SWAP ? blockIdx.x : blockIdx.z;
    const int n0 = (SWAP ? blockIdx.z : blockIdx.x) * BN;
    const long aoff = (long)(z / div) * AsN + (long)(z % div) * AsM;
    const long boff = (long)(z / div) * BsN + (long)(z % div) * BsM;
    const long coff = (long)(z / div) * CsN + (long)(z % div) * CsM;

    __shared__ short As[128 * BKP];
    __shared__ short Bs[BN * BKP];

    const int t = threadIdx.x;
    const int lane = t & 63;
    const int w = t >> 6, wr = w >> 1, wc = w & 1;

    f32x4 acc[4][NF];
    #pragma unroll
    for (int i = 0; i < 4; ++i)
        #pragma unroll
        for (int j = 0; j < NF; ++j) { acc[i][j].x = 0.f; acc[i][j].y = 0.f; acc[i][j].z = 0.f; acc[i][j].w = 0.f; }

    for (int k0 = 0; k0 < K; k0 += 32) {
        const long abase = AKBLK ? aoff + (long)(k0 >> 10) * AkStride + (k0 & 1023)
                                 : aoff + k0;
        const long bbase = boff + k0;
        #pragma unroll
        for (int itr = 0; itr < 2; ++itr) {
            const int idx = itr * 256 + t;
            const int row = idx >> 2, kq = idx & 3;
            const uint4 p = *(const uint4*)((const short*)Ap + abase + (long)row * lda + kq * 8);
            *(uint4*)&As[row * BKP + kq * 8] = p;
        }
        #pragma unroll
        for (int itr = 0; itr < BN / 64; ++itr) {
            const int idx = itr * 256 + t;
            const int row = idx >> 2, kq = idx & 3;
            uint4 p;
            if (B_F32) {
                const float* s = (const float*)Bp + bbase + (long)(n0 + row) * ldb + kq * 8;
                const float4 f0 = *(const float4*)s, f1 = *(const float4*)(s + 4);
                p.x = cvth2(f0.x, f0.y); p.y = cvth2(f0.z, f0.w);
                p.z = cvth2(f1.x, f1.y); p.w = cvth2(f1.z, f1.w);
            } else {
                p = *(const uint4*)((const short*)Bp + bbase + (long)(n0 + row) * ldb + kq * 8);
            }
            *(uint4*)&Bs[row * BKP + kq * 8] = p;
        }
        __syncthreads();

        f16x8 af[4], bfr[NF];
        #pragma unroll
        for (int mi = 0; mi < 4; ++mi)
            af[mi] = *(const f16x8*)&As[(wr * 64 + mi * 16 + (lane & 15)) * BKP + (lane >> 4) * 8];
        #pragma unroll
        for (int ni = 0; ni < NF; ++ni)
            bfr[ni] = *(const f16x8*)&Bs[(wc * (BN / 2) + ni * 16 + (lane & 15)) * BKP + (lane >> 4) * 8];
        #pragma unroll
        for (int mi = 0; mi < 4; ++mi)
            #pragma unroll
            for (int ni = 0; ni < NF; ++ni)
                acc[mi][ni] = __builtin_amdgcn_mfma_f32_16x16x32_f16(af[mi], bfr[ni], acc[mi][ni], 0, 0, 0);
        __syncthreads();
    }

    #pragma unroll
    for (int mi = 0; mi < 4; ++mi) {
        #pragma unroll
        for (int ni = 0; ni < NF; ++ni) {
            #pragma unroll
            for (int j = 0; j < 4; ++j) {
                const int row = wr * 64 + mi * 16 + (lane >> 4) * 4 + j;
                const int col = n0 + wc * (BN / 2) + ni * 16 + (lane & 15);
                float v = acc[mi][ni][j] * alpha;
                if (CMODE == 2) { v += bias[col]; v = fmaxf(v, 0.f); }
                if (CMODE == 2 || CMODE == 4) ((float*)Cp)[coff + (long)row * ldc + col] = v;
                else ((unsigned short*)Cp)[coff + (long)row * ldc + col] = cvth1(v);
            }
        }
    }
}

// ---------------------------------------------------------------------------
__global__ __launch_bounds__(256)
void splitk_reduce(const float* __restrict__ part, const float* __restrict__ bias,
                   float* __restrict__ out)
{
    const long idx = ((long)blockIdx.x * 256 + threadIdx.x) * 4;
    const int o = (int)(idx & 1023);
    const float4 p0 = *(const float4*)(part + idx);
    const float4 p1 = *(const float4*)(part + 2097152 + idx);
    const float4 p2 = *(const float4*)(part + 2 * 2097152 + idx);
    const float4 p3 = *(const float4*)(part + 3 * 2097152 + idx);
    const float4 bv = *(const float4*)(bias + o);
    float4 r;
    r.x = fmaxf(p0.x + p1.x + p2.x + p3.x + bv.x, 0.f);
    r.y = fmaxf(p0.y + p1.y + p2.y + p3.y + bv.y, 0.f);
    r.z = fmaxf(p0.z + p1.z + p2.z + p3.z + bv.z, 0.f);
    r.w = fmaxf(p0.w + p1.w + p2.w + p3.w + bv.w, 0.f);
    *(float4*)(out + idx) = r;
}

// ---------------------------------------------------------------------------
__global__ __launch_bounds__(256)
void cvt_otw(const float* __restrict__ in, unsigned short* __restrict__ out)
{
    const long i8 = ((long)blockIdx.x * 256 + threadIdx.x) * 8;
    const float4 f0 = *(const float4*)(in + i8), f1 = *(const float4*)(in + i8 + 4);
    uint4 p;
    p.x = cvth2(f0.x, f0.y); p.y = cvth2(f0.z, f0.w);
    p.z = cvth2(f1.x, f1.y); p.w = cvth2(f1.z, f1.w);
    *(uint4*)(out + i8) = p;
}

// ---------------------------------------------------------------------------
// GEMM1 fused (unchanged from R13).
// ---------------------------------------------------------------------------
__global__ __launch_bounds__(256)
void gemm1_exp(const unsigned short* __restrict__ otwH, const float* __restrict__ x,
               unsigned short* __restrict__ ekb, float* __restrict__ MiB)
{
    constexpr int BKP = 40;
    const int zb = blockIdx.x;                // b = n*4+m  (XCD-aligned)
    const int nn = zb >> 2, mm = zb & 3;
    const unsigned short* A = otwH + (long)mm * (OUT_SIZE * IN_DIM);
    const float* B = x + (long)nn * (IN_SIZE * IN_DIM);
    const int n0 = blockIdx.z * 128;

    __shared__ short As[128 * BKP];
    __shared__ short Bs[128 * BKP];
    __shared__ float colmax[2][128];

    const int t = threadIdx.x;
    const int lane = t & 63;
    const int w = t >> 6, wr = w >> 1, wc = w & 1;

    f32x4 acc[4][4];
    #pragma unroll
    for (int i = 0; i < 4; ++i)
        #pragma unroll
        for (int j = 0; j < 4; ++j) { acc[i][j].x = 0.f; acc[i][j].y = 0.f; acc[i][j].z = 0.f; acc[i][j].w = 0.f; }

    for (int k0 = 0; k0 < 1024; k0 += 32) {
        #pragma unroll
        for (int itr = 0; itr < 2; ++itr) {
            const int idx = itr * 256 + t;
            const int row = idx >> 2, kq = idx & 3;
            const uint4 p = *(const uint4*)(A + (long)row * 1024 + k0 + kq * 8);
            *(uint4*)&As[row * BKP + kq * 8] = p;
        }
        #pragma unroll
        for (int itr = 0; itr < 2; ++itr) {
            const int idx = itr * 256 + t;
            const int row = idx >> 2, kq = idx & 3;
            const float* s = B + (long)(n0 + row) * 1024 + k0 + kq * 8;
            const float4 f0 = *(const float4*)s, f1 = *(const float4*)(s + 4);
            uint4 p;
            p.x = cvth2(f0.x, f0.y); p.y = cvth2(f0.z, f0.w);
            p.z = cvth2(f1.x, f1.y); p.w = cvth2(f1.z, f1.w);
            *(uint4*)&Bs[row * BKP + kq * 8] = p;
        }
        __syncthreads();

        f16x8 af[4], bfr[4];
        #pragma unroll
        for (int mi = 0; mi < 4; ++mi)
            af[mi] = *(const f16x8*)&As[(wr * 64 + mi * 16 + (lane & 15)) * BKP + (lane >> 4) * 8];
        #pragma unroll
        for (int ni = 0; ni < 4; ++ni)
            bfr[ni] = *(const f16x8*)&Bs[(wc * 64 + ni * 16 + (lane & 15)) * BKP + (lane >> 4) * 8];
        #pragma unroll
        for (int mi = 0; mi < 4; ++mi)
            #pragma unroll
            for (int ni = 0; ni < 4; ++ni)
                acc[mi][ni] = __builtin_amdgcn_mfma_f32_16x16x32_f16(af[mi], bfr[ni], acc[mi][ni], 0, 0, 0);
        __syncthreads();
    }

    float lm[4];
    #pragma unroll
    for (int ni = 0; ni < 4; ++ni) {
        float mx = -INFINITY;
        #pragma unroll
        for (int mi = 0; mi < 4; ++mi)
            #pragma unroll
            for (int j = 0; j < 4; ++j) mx = fmaxf(mx, acc[mi][ni][j]);
        mx *= 10.0f;
        mx = fmaxf(mx, __shfl_xor(mx, 16, 64));
        mx = fmaxf(mx, __shfl_xor(mx, 32, 64));
        lm[ni] = mx;
    }
    if ((lane >> 4) == 0) {
        #pragma unroll
        for (int ni = 0; ni < 4; ++ni) colmax[wr][wc * 64 + ni * 16 + lane] = lm[ni];
    }
    __syncthreads();
    float cm[4];
    #pragma unroll
    for (int ni = 0; ni < 4; ++ni) {
        const int c = wc * 64 + ni * 16 + (lane & 15);
        cm[ni] = fmaxf(colmax[0][c], colmax[1][c]);
    }
    if (wr == 0 && (lane >> 4) == 0) {
        #pragma unroll
        for (int ni = 0; ni < 4; ++ni)
            MiB[(long)zb * 1024 + n0 + wc * 64 + ni * 16 + lane] = cm[ni];
    }
    unsigned short* ekz = ekb + (long)zb * (OUT_SIZE * IN_SIZE);
    #pragma unroll
    for (int mi = 0; mi < 4; ++mi) {
        #pragma unroll
        for (int ni = 0; ni < 4; ++ni) {
            const int col = n0 + wc * 64 + ni * 16 + (lane & 15);
            #pragma unroll
            for (int j = 0; j < 4; ++j) {
                const int row = wr * 64 + mi * 16 + (lane >> 4) * 4 + j;
                ekz[(long)row * 1024 + col] = bf16rne(__expf(fmaf(acc[mi][ni][j], 10.f, -cm[ni])));
            }
        }
    }
}

// ---------------------------------------------------------------------------
__global__ __launch_bounds__(256)
void transpose_cvt(const float* __restrict__ x, unsigned short* __restrict__ xT)
{
    const int n = blockIdx.z, i0 = blockIdx.y * 64, d0 = blockIdx.x * 64;
    const float* xs = x + (long)n * (IN_SIZE * IN_DIM);
    unsigned short* xo = xT + (long)n * (IN_SIZE * IN_DIM);
    __shared__ float tile[64][65];
    const int t = threadIdx.x;
    const int r = t >> 4, c4 = (t & 15) * 4;
    #pragma unroll
    for (int rr = 0; rr < 4; ++rr) {
        const float4 v = *(const float4*)(xs + (long)(i0 + rr * 16 + r) * IN_DIM + d0 + c4);
        *(float4*)&tile[rr * 16 + r][c4] = v;
    }
    __syncthreads();
    #pragma unroll
    for (int rr = 0; rr < 4; ++rr) {
        const int dl = rr * 16 + r;
        ushort4 o;
        o.x = cvth1(tile[c4 + 0][dl]); o.y = cvth1(tile[c4 + 1][dl]);
        o.z = cvth1(tile[c4 + 2][dl]); o.w = cvth1(tile[c4 + 3][dl]);
        *(ushort4*)(xo + (long)(d0 + dl) * IN_SIZE + i0 + c4) = o;
    }
}

// ---------------------------------------------------------------------------
// Sinkhorn v7: 1024 threads (phases halve), fused vmx/ev into combine
// (8 barriers/iter instead of 9), relaxed-load spin with ONE acquire after
// exit (the old acquire-in-loop invalidated L1 every poll). Siblings
// co-located per tile on XCD b%8 (grid 64x1x4). Math identical to v6.1.
// ---------------------------------------------------------------------------
__global__ __launch_bounds__(1024)
void sinkhorn_split(unsigned short* __restrict__ ekb,
                    const float* __restrict__ MiB,
                    float* __restrict__ xchg, unsigned int* __restrict__ ctr)
{
    const int b = blockIdx.x;          // tile 0..63 (XCD-aligned)
    const int q = blockIdx.z;          // i-quarter 0..3
    const int t = threadIdx.x;
    const int lane = t & 63, w = t >> 6;   // w in [0,16)

    __shared__ unsigned ekw[128 * 129];    // bf16-pairs, row stride 129 dw
    __shared__ float part_u[8][256];
    __shared__ float part_v[8][128];
    __shared__ float eu_l[256];
    __shared__ float v_s[128], ev_s[128];
    __shared__ float red8[8];
    __shared__ float wg_s;

    // ---- one-time ek load: [128 s][256 i-local], 1024 threads ----
    {
        const unsigned short* src = ekb + (long)b * 131072 + q * 256;
        #pragma unroll
        for (int j = 0; j < 4; ++j) {
            const int idx = t + 1024 * j;         // 0..4095
            const int s = idx >> 5, c8 = (idx & 31) * 8;
            const uint4 p = *(const uint4*)(src + (long)s * 1024 + c8);
            const int bd = s * 129 + (c8 >> 1);
            ekw[bd] = p.x; ekw[bd + 1] = p.y; ekw[bd + 2] = p.z; ekw[bd + 3] = p.w;
        }
    }
    float mi_t = 0.f, u_reg = 0.f, w_t = 0.f;
    if (t < 256) mi_t = MiB[(long)b * 1024 + q * 256 + t];
    if (t < 128) { v_s[t] = 0.f; ev_s[t] = 1.0f; }   // v=0 -> vmx=0, ev=1
    __syncthreads();

    const float A0 = -2.0794415416798357f;  // log(128/1024)
    float vmx = 0.f;

    for (int it = 0; it < MAX_ITER; ++it) {
        // ---- u-pass: part_u[sq][i] over 16 s each (8 groups) ----
        {
            const int p = t & 127, sq = t >> 7;
            float s0 = 0.f, s1 = 0.f;
            #pragma unroll
            for (int j = 0; j < 16; ++j) {
                const int s = sq * 16 + j;
                const unsigned e = ekw[s * 129 + p];
                const float evv = ev_s[s];
                s0 = fmaf(__uint_as_float(e << 16),          evv, s0);
                s1 = fmaf(__uint_as_float(e & 0xffff0000u),  evv, s1);
            }
            part_u[sq][2 * p]     = s0;
            part_u[sq][2 * p + 1] = s1;
        }
        __syncthreads();                                   // C

        // ---- u update (t<256 owns i-local = t), wmx partials ----
        if (t < 256) {
            float S = part_u[0][t];
            #pragma unroll
            for (int g = 1; g < 8; ++g) S += part_u[g][t];
            const float un = A0 - u_reg - mi_t - vmx - __logf(S);
            u_reg = un;
            w_t = mi_t + un;
            float wl = w_t;
            #pragma unroll
            for (int m = 1; m < 64; m <<= 1) wl = fmaxf(wl, __shfl_xor(wl, m, 64));
            if (lane == 0) red8[4 + w] = wl;               // waves 0..3
        }
        __syncthreads();                                   // D
        const float wmx_l = fmaxf(fmaxf(red8[4], red8[5]), fmaxf(red8[6], red8[7]));
        if (t < 256) eu_l[t] = __expf(w_t - wmx_l);
        __syncthreads();                                   // E

        // ---- v-pass: part_v[g][s] over 16 i-pairs each (8 groups) ----
        {
            const int s = t & 127, g = t >> 7;
            float acc = 0.f;
            #pragma unroll
            for (int j = 0; j < 16; ++j) {
                const int p = 16 * g + j;
                const unsigned e = ekw[s * 129 + p];
                const float2 eup = *(const float2*)&eu_l[2 * p];
                acc = fmaf(__uint_as_float(e << 16),         eup.x, acc);
                acc = fmaf(__uint_as_float(e & 0xffff0000u), eup.y, acc);
            }
            part_v[g][s] = acc;
        }
        __syncthreads();                                   // F

        // ---- publish (cp_local, wmx_l), arrive, relaxed-spin ----
        float* slot = xchg + ((long)(b * MAX_ITER + it) * 4 + q) * 160;
        if (t < 128) {
            float cp_l = part_v[0][t];
            #pragma unroll
            for (int g = 1; g < 8; ++g) cp_l += part_v[g][t];
            __hip_atomic_store(slot + t, cp_l, __ATOMIC_RELAXED, __HIP_MEMORY_SCOPE_AGENT);
        }
        if (t == 0)
            __hip_atomic_store(slot + 128, wmx_l, __ATOMIC_RELAXED, __HIP_MEMORY_SCOPE_AGENT);
        __syncthreads();                                   // G (drains stores)
        if (t == 0) {
            unsigned int* c = ctr + b * MAX_ITER + it;
            __hip_atomic_fetch_add(c, 1u, __ATOMIC_RELEASE, __HIP_MEMORY_SCOPE_AGENT);
            while (__hip_atomic_load(c, __ATOMIC_RELAXED, __HIP_MEMORY_SCOPE_AGENT) < 4u) {}
            (void)__hip_atomic_load(c, __ATOMIC_ACQUIRE, __HIP_MEMORY_SCOPE_AGENT);
        }
        __syncthreads();                                   // H

        // ---- combine + fused next-iter vmx/ev ----
        if (t < 128) {
            float* base = xchg + (long)(b * MAX_ITER + it) * 4 * 160;
            const float w0 = __hip_atomic_load(base + 0 * 160 + 128, __ATOMIC_RELAXED, __HIP_MEMORY_SCOPE_AGENT);
            const float w1 = __hip_atomic_load(base + 1 * 160 + 128, __ATOMIC_RELAXED, __HIP_MEMORY_SCOPE_AGENT);
            const float w2 = __hip_atomic_load(base + 2 * 160 + 128, __ATOMIC_RELAXED, __HIP_MEMORY_SCOPE_AGENT);
            const float w3 = __hip_atomic_load(base + 3 * 160 + 128, __ATOMIC_RELAXED, __HIP_MEMORY_SCOPE_AGENT);
            const float wg = fmaxf(fmaxf(w0, w1), fmaxf(w2, w3));
            const float c0 = __hip_atomic_load(base + 0 * 160 + t, __ATOMIC_RELAXED, __HIP_MEMORY_SCOPE_AGENT);
            const float c1 = __hip_atomic_load(base + 1 * 160 + t, __ATOMIC_RELAXED, __HIP_MEMORY_SCOPE_AGENT);
            const float c2 = __hip_atomic_load(base + 2 * 160 + t, __ATOMIC_RELAXED, __HIP_MEMORY_SCOPE_AGENT);
            const float c3 = __hip_atomic_load(base + 3 * 160 + t, __ATOMIC_RELAXED, __HIP_MEMORY_SCOPE_AGENT);
            const float cp = c0 * __expf(w0 - wg) + c1 * __expf(w1 - wg)
                           + c2 * __expf(w2 - wg) + c3 * __expf(w3 - wg);
            const float vn = -v_s[t] - wg - __logf(cp);
            v_s[t] = vn;
            if (t == 0) wg_s = wg;
            float xv = vn;
            #pragma unroll
            for (int m = 1; m < 64; m <<= 1) xv = fmaxf(xv, __shfl_xor(xv, m, 64));
            if (lane == 0) red8[w] = xv;                   // waves 0..1
        }
        __syncthreads();                                   // I
        vmx = fmaxf(red8[0], red8[1]);
        if (t < 128) ev_s[t] = __expf(v_s[t] - vmx);
        __syncthreads();                                   // J
    }

    // ---- write T fp16 over own ek slice: T = ek * eu[i] * ecv[s] ----
    const float wg = wg_s;
    if (t < 256) eu_l[t] = __expf(w_t - wg);          // global-normalized eu
    if (t < 128) ev_s[t] = __expf(v_s[t] + wg);       // ecv
    __syncthreads();
    unsigned short* To = ekb + (long)b * 131072 + q * 256;
    #pragma unroll
    for (int j = 0; j < 16; ++j) {
        const int idx = t + 1024 * j;         // 0..16383
        const int s  = idx >> 7;              // 0..127
        const int ip = idx & 127;             // bf16-pair index
        const unsigned e = ekw[s * 129 + ip];
        const float2 eup = *(const float2*)&eu_l[2 * ip];
        const float ec = ev_s[s];
        const float lo = __uint_as_float(e << 16)         * eup.x * ec;
        const float hi = __uint_as_float(e & 0xffff0000u) * eup.y * ec;
        *(unsigned*)(To + (long)s * 1024 + ip * 2) = cvth2(lo, hi);
    }
}

// ---------------------------------------------------------------------------
extern "C" void kernel_launch(void* const* d_in, const int* in_sizes, int n_in,
                              void* d_out, int out_size, void* d_ws, size_t ws_size,
                              hipStream_t stream)
{
    const float* x     = (const float*)d_in[0];   // [16][1024][1024]
    const float* otw   = (const float*)d_in[1];   // [4][128][1024]
    const float* lin_w = (const float*)d_in[2];   // [1024][4096]
    const float* lin_b = (const float*)d_in[3];   // [1024]
    float* out = (float*)d_out;                   // [16][128][1024] fp32 (8 MB)

    // ws (64 MB): [0,32M) xT fp16 (dead after GEMM2 -> split-K partials)
    //             [32M,48M) ek bf16 -> overwritten in-place with T fp16
    //             [48M,64M) feat fp16
    unsigned short* xT   = (unsigned short*)d_ws;
    unsigned short* ekb  = xT + 16777216;
    unsigned short* feat = ekb + 8388608;
    float* partial = (float*)d_ws;
    // d_out scratch (fully overwritten by splitk_reduce):
    //   Mi [64][1024] @0 ; xchg [64][10][4][160] @131072 ; ctr @655360 ;
    //   otwH fp16 [512][1024] @786432 (floats)
    float* MiB  = (float*)d_out;
    float* xchg = MiB + 131072;
    unsigned int* ctrB = (unsigned int*)(MiB + 655360);
    unsigned short* otwH = (unsigned short*)(MiB + 786432);

    // reset arrival counters (stream-ordered, capture-legal)
    hipMemsetAsync(ctrB, 0, 64 * MAX_ITER * sizeof(unsigned int), stream);

    // -1) otw fp32 -> fp16
    cvt_otw<<<dim3(256), 256, 0, stream>>>(otw, otwH);

    // 0) x -> xT fp16
    transpose_cvt<<<dim3(16, 16, NB), 256, 0, stream>>>(x, xT);

    // 1) fused K-GEMM + colmax + exp -> ek bf16, Mi
    gemm1_exp<<<dim3(64, 1, 8), 256, 0, stream>>>(otwH, x, ekb, MiB);

    // 2) Sinkhorn v7: 1024 threads, co-located siblings, fused phases
    sinkhorn_split<<<dim3(64, 1, 4), 1024, 0, stream>>>(ekb, MiB, xchg, ctrB);

    // 3) feat = T . xT^T (plain fp16 GEMM, NF=4 grid (64,1,8), XCD-aligned)
    mfma_gemm<0, false, 1, 4, false, true><<<dim3(64, 1, 8), 256, 0, stream>>>(
        ekb, xT, nullptr, feat,
        1024, 1024, 1024, 1024, 4,
        524288, 131072, 1048576, 0, 524288, 131072, 0, 1.0f);

    // 4) split-K x4 GEMM3
    mfma_gemm<0, true, 4, 2, false, false><<<dim3(16, 1, 64), 256, 0, stream>>>(
        feat, lin_w, nullptr, partial,
        1024, 1024, 4096, 1024, 16,
        131072, 524288, 1024, 0, 2097152, 131072, 0, 1.0f);

    // 5) out = relu(sum_ks partial + bias)
    splitk_reduce<<<dim3(2048), 256, 0, stream>>>(partial, lin_b, out);
}

// Round 16
// 208.250 us; speedup vs baseline: 1.1036x; 1.0097x over previous
//
#include <hip/hip_runtime.h>
#include <math.h>

#define EPSV 0.1f
#define MAX_ITER 10
constexpr int NB       = 16;
constexpr int IN_SIZE  = 1024;
constexpr int IN_DIM   = 1024;
constexpr int HEADS    = 4;
constexpr int OUT_SIZE = 128;
constexpr int OUT_DIM  = 1024;

typedef __attribute__((ext_vector_type(8))) _Float16 f16x8;
typedef __attribute__((ext_vector_type(4))) float f32x4;

__device__ __forceinline__ unsigned cvth2(float lo, float hi) {
    _Float16 a = (_Float16)lo, b = (_Float16)hi;
    unsigned short ua = *(unsigned short*)&a, ub = *(unsigned short*)&b;
    return (unsigned)ua | ((unsigned)ub << 16);
}
__device__ __forceinline__ unsigned short cvth1(float f) {
    _Float16 a = (_Float16)f;
    return *(unsigned short*)&a;
}
__device__ __forceinline__ unsigned short bf16rne(float f) {
    unsigned a = __float_as_uint(f);
    return (unsigned short)((a + 0x7fffu + ((a >> 16) & 1u)) >> 16);
}
// async global->LDS, 16 B per lane: HW writes lane l at ldsbase + l*16.
__device__ __forceinline__ void glds16(const void* g, void* l) {
    __builtin_amdgcn_global_load_lds(
        (const __attribute__((address_space(1))) unsigned int*)g,
        (__attribute__((address_space(3))) unsigned int*)l, 16, 0, 0);
}

// ---------------------------------------------------------------------------
// MFMA fp16 GEMM, M fixed 128, A always fp16 via global_load_lds (linear
// LDS [rows][32], m97 pattern). B: fp16 glds, or fp32 reg-staged (padded).
// CMODE: 1 = fp16 store, 2 = f32+bias+relu, 4 = f32 raw (split-K partial)
// SWAP : batch index from blockIdx.x (XCD-aligned), n0 from blockIdx.z.
// ---------------------------------------------------------------------------
template<bool B_F32, int CMODE, int NF, bool AKBLK, bool SWAP>
__global__ __launch_bounds__(256)
void mfma_gemm(const void* __restrict__ Ap, const void* __restrict__ Bp,
               const float* __restrict__ bias, void* __restrict__ Cp,
               int K, int lda, int ldb, int ldc, int div,
               long AsN, long AsM, long BsN, long BsM, long CsN, long CsM,
               long AkStride, float alpha)
{
    constexpr int BN   = NF * 32;
    constexpr int BSTR = B_F32 ? 40 : 32;   // B LDS row stride (elems)
    const int z  = SWAP ? blockIdx.x : blockIdx.z;
    const int n0 = (SWAP ? blockIdx.z : blockIdx.x) * BN;
    const long aoff = (long)(z / div) * AsN + (long)(z % div) * AsM;
    const long boff = (long)(z / div) * BsN + (long)(z % div) * BsM;
    const long coff = (long)(z / div) * CsN + (long)(z % div) * CsM;

    __shared__ short As[128 * 32];
    __shared__ short Bs[BN * BSTR];

    const int t = threadIdx.x;
    const int lane = t & 63;
    const int w = t >> 6, wr = w >> 1, wc = w & 1;

    f32x4 acc[4][NF];
    #pragma unroll
    for (int i = 0; i < 4; ++i)
        #pragma unroll
        for (int j = 0; j < NF; ++j) { acc[i][j].x = 0.f; acc[i][j].y = 0.f; acc[i][j].z = 0.f; acc[i][j].w = 0.f; }

    const int lrow = lane >> 2, lce = (lane & 3) * 8;   // glds lane mapping

    for (int k0 = 0; k0 < K; k0 += 32) {
        const long abase = AKBLK ? aoff + (long)(k0 >> 10) * AkStride + (k0 & 1023)
                                 : aoff + k0;
        const long bbase = boff + k0;
        // ---- stage A: 8 glds (2 per wave), rows w*32+j*16 .. +16 ----
        #pragma unroll
        for (int j = 0; j < 2; ++j) {
            const int row0 = (w * 2 + j) * 16;
            glds16((const short*)Ap + abase + (long)(row0 + lrow) * lda + lce,
                   &As[row0 * 32]);
        }
        // ---- stage B ----
        if (B_F32) {
            #pragma unroll
            for (int itr = 0; itr < BN / 64; ++itr) {
                const int idx = itr * 256 + t;
                const int row = idx >> 2, kq = idx & 3;
                const float* s = (const float*)Bp + bbase + (long)(n0 + row) * ldb + kq * 8;
                const float4 f0 = *(const float4*)s, f1 = *(const float4*)(s + 4);
                uint4 p;
                p.x = cvth2(f0.x, f0.y); p.y = cvth2(f0.z, f0.w);
                p.z = cvth2(f1.x, f1.y); p.w = cvth2(f1.z, f1.w);
                *(uint4*)&Bs[row * BSTR + kq * 8] = p;
            }
        } else {
            #pragma unroll
            for (int j = 0; j < BN / 64; ++j) {
                const int row0 = (w * (BN / 64) + j) * 16;
                glds16((const short*)Bp + bbase + (long)(n0 + row0 + lrow) * ldb + lce,
                       &Bs[row0 * 32]);
            }
        }
        __syncthreads();

        f16x8 af[4], bfr[NF];
        #pragma unroll
        for (int mi = 0; mi < 4; ++mi)
            af[mi] = *(const f16x8*)&As[(wr * 64 + mi * 16 + (lane & 15)) * 32 + (lane >> 4) * 8];
        #pragma unroll
        for (int ni = 0; ni < NF; ++ni)
            bfr[ni] = *(const f16x8*)&Bs[(wc * (BN / 2) + ni * 16 + (lane & 15)) * BSTR + (lane >> 4) * 8];
        #pragma unroll
        for (int mi = 0; mi < 4; ++mi)
            #pragma unroll
            for (int ni = 0; ni < NF; ++ni)
                acc[mi][ni] = __builtin_amdgcn_mfma_f32_16x16x32_f16(af[mi], bfr[ni], acc[mi][ni], 0, 0, 0);
        __syncthreads();
    }

    #pragma unroll
    for (int mi = 0; mi < 4; ++mi) {
        #pragma unroll
        for (int ni = 0; ni < NF; ++ni) {
            #pragma unroll
            for (int j = 0; j < 4; ++j) {
                const int row = wr * 64 + mi * 16 + (lane >> 4) * 4 + j;
                const int col = n0 + wc * (BN / 2) + ni * 16 + (lane & 15);
                float v = acc[mi][ni][j] * alpha;
                if (CMODE == 2) { v += bias[col]; v = fmaxf(v, 0.f); }
                if (CMODE == 2 || CMODE == 4) ((float*)Cp)[coff + (long)row * ldc + col] = v;
                else ((unsigned short*)Cp)[coff + (long)row * ldc + col] = cvth1(v);
            }
        }
    }
}

// ---------------------------------------------------------------------------
__global__ __launch_bounds__(256)
void splitk_reduce(const float* __restrict__ part, const float* __restrict__ bias,
                   float* __restrict__ out)
{
    const long idx = ((long)blockIdx.x * 256 + threadIdx.x) * 4;
    const int o = (int)(idx & 1023);
    const float4 p0 = *(const float4*)(part + idx);
    const float4 p1 = *(const float4*)(part + 2097152 + idx);
    const float4 p2 = *(const float4*)(part + 2 * 2097152 + idx);
    const float4 p3 = *(const float4*)(part + 3 * 2097152 + idx);
    const float4 bv = *(const float4*)(bias + o);
    float4 r;
    r.x = fmaxf(p0.x + p1.x + p2.x + p3.x + bv.x, 0.f);
    r.y = fmaxf(p0.y + p1.y + p2.y + p3.y + bv.y, 0.f);
    r.z = fmaxf(p0.z + p1.z + p2.z + p3.z + bv.z, 0.f);
    r.w = fmaxf(p0.w + p1.w + p2.w + p3.w + bv.w, 0.f);
    *(float4*)(out + idx) = r;
}

// ---------------------------------------------------------------------------
// generic fp32 -> fp16 elementwise (8 elems/thread)
// ---------------------------------------------------------------------------
__global__ __launch_bounds__(256)
void cvt_f16(const float* __restrict__ in, unsigned short* __restrict__ out)
{
    const long i8 = ((long)blockIdx.x * 256 + threadIdx.x) * 8;
    const float4 f0 = *(const float4*)(in + i8), f1 = *(const float4*)(in + i8 + 4);
    uint4 p;
    p.x = cvth2(f0.x, f0.y); p.y = cvth2(f0.z, f0.w);
    p.z = cvth2(f1.x, f1.y); p.w = cvth2(f1.z, f1.w);
    *(uint4*)(out + i8) = p;
}

// ---------------------------------------------------------------------------
// GEMM1 fused: K = 10*otwH . xH^T per (b, 128-i chunk); colmax over all
// 128 s -> Mi; ek = bf16(exp(K-Mi)). Both operands fp16 via glds, linear
// LDS. XCD-aligned: tile = blockIdx.x (grid 64,1,8).
// ---------------------------------------------------------------------------
__global__ __launch_bounds__(256)
void gemm1_exp(const unsigned short* __restrict__ otwH,
               const unsigned short* __restrict__ xH,
               unsigned short* __restrict__ ekb, float* __restrict__ MiB)
{
    const int zb = blockIdx.x;                // b = n*4+m  (XCD-aligned)
    const int nn = zb >> 2, mm = zb & 3;
    const unsigned short* A = otwH + (long)mm * (OUT_SIZE * IN_DIM);
    const unsigned short* B = xH + (long)nn * (IN_SIZE * IN_DIM);
    const int n0 = blockIdx.z * 128;          // i-chunk

    __shared__ short As[128 * 32];
    __shared__ short Bs[128 * 32];
    __shared__ float colmax[2][128];

    const int t = threadIdx.x;
    const int lane = t & 63;
    const int w = t >> 6, wr = w >> 1, wc = w & 1;
    const int lrow = lane >> 2, lce = (lane & 3) * 8;

    f32x4 acc[4][4];
    #pragma unroll
    for (int i = 0; i < 4; ++i)
        #pragma unroll
        for (int j = 0; j < 4; ++j) { acc[i][j].x = 0.f; acc[i][j].y = 0.f; acc[i][j].z = 0.f; acc[i][j].w = 0.f; }

    for (int k0 = 0; k0 < 1024; k0 += 32) {
        #pragma unroll
        for (int j = 0; j < 2; ++j) {
            const int row0 = (w * 2 + j) * 16;
            glds16(A + (long)(row0 + lrow) * 1024 + k0 + lce, &As[row0 * 32]);
        }
        #pragma unroll
        for (int j = 0; j < 2; ++j) {
            const int row0 = (w * 2 + j) * 16;
            glds16(B + (long)(n0 + row0 + lrow) * 1024 + k0 + lce, &Bs[row0 * 32]);
        }
        __syncthreads();

        f16x8 af[4], bfr[4];
        #pragma unroll
        for (int mi = 0; mi < 4; ++mi)
            af[mi] = *(const f16x8*)&As[(wr * 64 + mi * 16 + (lane & 15)) * 32 + (lane >> 4) * 8];
        #pragma unroll
        for (int ni = 0; ni < 4; ++ni)
            bfr[ni] = *(const f16x8*)&Bs[(wc * 64 + ni * 16 + (lane & 15)) * 32 + (lane >> 4) * 8];
        #pragma unroll
        for (int mi = 0; mi < 4; ++mi)
            #pragma unroll
            for (int ni = 0; ni < 4; ++ni)
                acc[mi][ni] = __builtin_amdgcn_mfma_f32_16x16x32_f16(af[mi], bfr[ni], acc[mi][ni], 0, 0, 0);
        __syncthreads();
    }

    float lm[4];
    #pragma unroll
    for (int ni = 0; ni < 4; ++ni) {
        float mx = -INFINITY;
        #pragma unroll
        for (int mi = 0; mi < 4; ++mi)
            #pragma unroll
            for (int j = 0; j < 4; ++j) mx = fmaxf(mx, acc[mi][ni][j]);
        mx *= 10.0f;
        mx = fmaxf(mx, __shfl_xor(mx, 16, 64));
        mx = fmaxf(mx, __shfl_xor(mx, 32, 64));
        lm[ni] = mx;
    }
    if ((lane >> 4) == 0) {
        #pragma unroll
        for (int ni = 0; ni < 4; ++ni) colmax[wr][wc * 64 + ni * 16 + lane] = lm[ni];
    }
    __syncthreads();
    float cm[4];
    #pragma unroll
    for (int ni = 0; ni < 4; ++ni) {
        const int c = wc * 64 + ni * 16 + (lane & 15);
        cm[ni] = fmaxf(colmax[0][c], colmax[1][c]);
    }
    if (wr == 0 && (lane >> 4) == 0) {
        #pragma unroll
        for (int ni = 0; ni < 4; ++ni)
            MiB[(long)zb * 1024 + n0 + wc * 64 + ni * 16 + lane] = cm[ni];
    }
    unsigned short* ekz = ekb + (long)zb * (OUT_SIZE * IN_SIZE);
    #pragma unroll
    for (int mi = 0; mi < 4; ++mi) {
        #pragma unroll
        for (int ni = 0; ni < 4; ++ni) {
            const int col = n0 + wc * 64 + ni * 16 + (lane & 15);
            #pragma unroll
            for (int j = 0; j < 4; ++j) {
                const int row = wr * 64 + mi * 16 + (lane >> 4) * 4 + j;
                ekz[(long)row * 1024 + col] = bf16rne(__expf(fmaf(acc[mi][ni][j], 10.f, -cm[ni])));
            }
        }
    }
}

// ---------------------------------------------------------------------------
__global__ __launch_bounds__(256)
void transpose_cvt(const float* __restrict__ x, unsigned short* __restrict__ xT)
{
    const int n = blockIdx.z, i0 = blockIdx.y * 64, d0 = blockIdx.x * 64;
    const float* xs = x + (long)n * (IN_SIZE * IN_DIM);
    unsigned short* xo = xT + (long)n * (IN_SIZE * IN_DIM);
    __shared__ float tile[64][65];
    const int t = threadIdx.x;
    const int r = t >> 4, c4 = (t & 15) * 4;
    #pragma unroll
    for (int rr = 0; rr < 4; ++rr) {
        const float4 v = *(const float4*)(xs + (long)(i0 + rr * 16 + r) * IN_DIM + d0 + c4);
        *(float4*)&tile[rr * 16 + r][c4] = v;
    }
    __syncthreads();
    #pragma unroll
    for (int rr = 0; rr < 4; ++rr) {
        const int dl = rr * 16 + r;
        ushort4 o;
        o.x = cvth1(tile[c4 + 0][dl]); o.y = cvth1(tile[c4 + 1][dl]);
        o.z = cvth1(tile[c4 + 2][dl]); o.w = cvth1(tile[c4 + 3][dl]);
        *(ushort4*)(xo + (long)(d0 + dl) * IN_SIZE + i0 + c4) = o;
    }
}

// ---------------------------------------------------------------------------
// Sinkhorn v7 (unchanged from R14): 1024 threads, co-located siblings on
// XCD b%8 (grid 64x1x4), 8 barriers/iter, relaxed spin, writes T fp16
// over the dead ek region.
// ---------------------------------------------------------------------------
__global__ __launch_bounds__(1024)
void sinkhorn_split(unsigned short* __restrict__ ekb,
                    const float* __restrict__ MiB,
                    float* __restrict__ xchg, unsigned int* __restrict__ ctr)
{
    const int b = blockIdx.x;          // tile 0..63 (XCD-aligned)
    const int q = blockIdx.z;          // i-quarter 0..3
    const int t = threadIdx.x;
    const int lane = t & 63, w = t >> 6;

    __shared__ unsigned ekw[128 * 129];
    __shared__ float part_u[8][256];
    __shared__ float part_v[8][128];
    __shared__ float eu_l[256];
    __shared__ float v_s[128], ev_s[128];
    __shared__ float red8[8];
    __shared__ float wg_s;

    {
        const unsigned short* src = ekb + (long)b * 131072 + q * 256;
        #pragma unroll
        for (int j = 0; j < 4; ++j) {
            const int idx = t + 1024 * j;
            const int s = idx >> 5, c8 = (idx & 31) * 8;
            const uint4 p = *(const uint4*)(src + (long)s * 1024 + c8);
            const int bd = s * 129 + (c8 >> 1);
            ekw[bd] = p.x; ekw[bd + 1] = p.y; ekw[bd + 2] = p.z; ekw[bd + 3] = p.w;
        }
    }
    float mi_t = 0.f, u_reg = 0.f, w_t = 0.f;
    if (t < 256) mi_t = MiB[(long)b * 1024 + q * 256 + t];
    if (t < 128) { v_s[t] = 0.f; ev_s[t] = 1.0f; }
    __syncthreads();

    const float A0 = -2.0794415416798357f;
    float vmx = 0.f;

    for (int it = 0; it < MAX_ITER; ++it) {
        {
            const int p = t & 127, sq = t >> 7;
            float s0 = 0.f, s1 = 0.f;
            #pragma unroll
            for (int j = 0; j < 16; ++j) {
                const int s = sq * 16 + j;
                const unsigned e = ekw[s * 129 + p];
                const float evv = ev_s[s];
                s0 = fmaf(__uint_as_float(e << 16),          evv, s0);
                s1 = fmaf(__uint_as_float(e & 0xffff0000u),  evv, s1);
            }
            part_u[sq][2 * p]     = s0;
            part_u[sq][2 * p + 1] = s1;
        }
        __syncthreads();

        if (t < 256) {
            float S = part_u[0][t];
            #pragma unroll
            for (int g = 1; g < 8; ++g) S += part_u[g][t];
            const float un = A0 - u_reg - mi_t - vmx - __logf(S);
            u_reg = un;
            w_t = mi_t + un;
            float wl = w_t;
            #pragma unroll
            for (int m = 1; m < 64; m <<= 1) wl = fmaxf(wl, __shfl_xor(wl, m, 64));
            if (lane == 0) red8[4 + w] = wl;
        }
        __syncthreads();
        const float wmx_l = fmaxf(fmaxf(red8[4], red8[5]), fmaxf(red8[6], red8[7]));
        if (t < 256) eu_l[t] = __expf(w_t - wmx_l);
        __syncthreads();

        {
            const int s = t & 127, g = t >> 7;
            float acc = 0.f;
            #pragma unroll
            for (int j = 0; j < 16; ++j) {
                const int p = 16 * g + j;
                const unsigned e = ekw[s * 129 + p];
                const float2 eup = *(const float2*)&eu_l[2 * p];
                acc = fmaf(__uint_as_float(e << 16),         eup.x, acc);
                acc = fmaf(__uint_as_float(e & 0xffff0000u), eup.y, acc);
            }
            part_v[g][s] = acc;
        }
        __syncthreads();

        float* slot = xchg + ((long)(b * MAX_ITER + it) * 4 + q) * 160;
        if (t < 128) {
            float cp_l = part_v[0][t];
            #pragma unroll
            for (int g = 1; g < 8; ++g) cp_l += part_v[g][t];
            __hip_atomic_store(slot + t, cp_l, __ATOMIC_RELAXED, __HIP_MEMORY_SCOPE_AGENT);
        }
        if (t == 0)
            __hip_atomic_store(slot + 128, wmx_l, __ATOMIC_RELAXED, __HIP_MEMORY_SCOPE_AGENT);
        __syncthreads();
        if (t == 0) {
            unsigned int* c = ctr + b * MAX_ITER + it;
            __hip_atomic_fetch_add(c, 1u, __ATOMIC_RELEASE, __HIP_MEMORY_SCOPE_AGENT);
            while (__hip_atomic_load(c, __ATOMIC_RELAXED, __HIP_MEMORY_SCOPE_AGENT) < 4u) {}
            (void)__hip_atomic_load(c, __ATOMIC_ACQUIRE, __HIP_MEMORY_SCOPE_AGENT);
        }
        __syncthreads();

        if (t < 128) {
            float* base = xchg + (long)(b * MAX_ITER + it) * 4 * 160;
            const float w0 = __hip_atomic_load(base + 0 * 160 + 128, __ATOMIC_RELAXED, __HIP_MEMORY_SCOPE_AGENT);
            const float w1 = __hip_atomic_load(base + 1 * 160 + 128, __ATOMIC_RELAXED, __HIP_MEMORY_SCOPE_AGENT);
            const float w2 = __hip_atomic_load(base + 2 * 160 + 128, __ATOMIC_RELAXED, __HIP_MEMORY_SCOPE_AGENT);
            const float w3 = __hip_atomic_load(base + 3 * 160 + 128, __ATOMIC_RELAXED, __HIP_MEMORY_SCOPE_AGENT);
            const float wg = fmaxf(fmaxf(w0, w1), fmaxf(w2, w3));
            const float c0 = __hip_atomic_load(base + 0 * 160 + t, __ATOMIC_RELAXED, __HIP_MEMORY_SCOPE_AGENT);
            const float c1 = __hip_atomic_load(base + 1 * 160 + t, __ATOMIC_RELAXED, __HIP_MEMORY_SCOPE_AGENT);
            const float c2 = __hip_atomic_load(base + 2 * 160 + t, __ATOMIC_RELAXED, __HIP_MEMORY_SCOPE_AGENT);
            const float c3 = __hip_atomic_load(base + 3 * 160 + t, __ATOMIC_RELAXED, __HIP_MEMORY_SCOPE_AGENT);
            const float cp = c0 * __expf(w0 - wg) + c1 * __expf(w1 - wg)
                           + c2 * __expf(w2 - wg) + c3 * __expf(w3 - wg);
            const float vn = -v_s[t] - wg - __logf(cp);
            v_s[t] = vn;
            if (t == 0) wg_s = wg;
            float xv = vn;
            #pragma unroll
            for (int m = 1; m < 64; m <<= 1) xv = fmaxf(xv, __shfl_xor(xv, m, 64));
            if (lane == 0) red8[w] = xv;
        }
        __syncthreads();
        vmx = fmaxf(red8[0], red8[1]);
        if (t < 128) ev_s[t] = __expf(v_s[t] - vmx);
        __syncthreads();
    }

    const float wg = wg_s;
    if (t < 256) eu_l[t] = __expf(w_t - wg);
    if (t < 128) ev_s[t] = __expf(v_s[t] + wg);
    __syncthreads();
    unsigned short* To = ekb + (long)b * 131072 + q * 256;
    #pragma unroll
    for (int j = 0; j < 16; ++j) {
        const int idx = t + 1024 * j;
        const int s  = idx >> 7;
        const int ip = idx & 127;
        const unsigned e = ekw[s * 129 + ip];
        const float2 eup = *(const float2*)&eu_l[2 * ip];
        const float ec = ev_s[s];
        const float lo = __uint_as_float(e << 16)         * eup.x * ec;
        const float hi = __uint_as_float(e & 0xffff0000u) * eup.y * ec;
        *(unsigned*)(To + (long)s * 1024 + ip * 2) = cvth2(lo, hi);
    }
}

// ---------------------------------------------------------------------------
extern "C" void kernel_launch(void* const* d_in, const int* in_sizes, int n_in,
                              void* d_out, int out_size, void* d_ws, size_t ws_size,
                              hipStream_t stream)
{
    const float* x     = (const float*)d_in[0];   // [16][1024][1024]
    const float* otw   = (const float*)d_in[1];   // [4][128][1024]
    const float* lin_w = (const float*)d_in[2];   // [1024][4096]
    const float* lin_b = (const float*)d_in[3];   // [1024]
    float* out = (float*)d_out;                   // [16][128][1024] fp32 (8 MB)

    // ws (64 MB): [0,32M) = xH fp16 (gemm1) -> xT fp16 (GEMM2) -> partial f32
    //             [32M,48M) ek bf16 -> T fp16 in-place; [48M,64M) feat fp16
    unsigned short* xH   = (unsigned short*)d_ws;
    unsigned short* xT   = (unsigned short*)d_ws;
    unsigned short* ekb  = xH + 16777216;
    unsigned short* feat = ekb + 8388608;
    float* partial = (float*)d_ws;
    // d_out scratch (fully overwritten by splitk_reduce):
    //   Mi [64][1024] @0 ; xchg @131072 ; ctr @655360 ; otwH fp16 @786432
    float* MiB  = (float*)d_out;
    float* xchg = MiB + 131072;
    unsigned int* ctrB = (unsigned int*)(MiB + 655360);
    unsigned short* otwH = (unsigned short*)(MiB + 786432);

    hipMemsetAsync(ctrB, 0, 64 * MAX_ITER * sizeof(unsigned int), stream);

    // -1) otw -> fp16 ; x -> xH fp16 (linear)
    cvt_f16<<<dim3(256), 256, 0, stream>>>(otw, otwH);
    cvt_f16<<<dim3(8192), 256, 0, stream>>>(x, xH);   // 16M elems... 16*1024*1024/2048

    // 1) fused K-GEMM + colmax + exp -> ek bf16, Mi (glds both operands)
    gemm1_exp<<<dim3(64, 1, 8), 256, 0, stream>>>(otwH, xH, ekb, MiB);

    // 0') x -> xT fp16 over dead xH
    transpose_cvt<<<dim3(16, 16, NB), 256, 0, stream>>>(x, xT);

    // 2) Sinkhorn v7 -> T fp16 over ek
    sinkhorn_split<<<dim3(64, 1, 4), 1024, 0, stream>>>(ekb, MiB, xchg, ctrB);

    // 3) feat = T . xT^T (both fp16 glds, NF=4 grid (64,1,8), XCD-aligned)
    mfma_gemm<false, 1, 4, false, true><<<dim3(64, 1, 8), 256, 0, stream>>>(
        ekb, xT, nullptr, feat,
        1024, 1024, 1024, 1024, 4,
        524288, 131072, 1048576, 0, 524288, 131072, 0, 1.0f);

    // 4) split-K x4 GEMM3: A glds, B fp32 reg-staged
    mfma_gemm<true, 4, 2, false, false><<<dim3(16, 1, 64), 256, 0, stream>>>(
        feat, lin_w, nullptr, partial,
        1024, 1024, 4096, 1024, 16,
        131072, 524288, 1024, 0, 2097152, 131072, 0, 1.0f);

    // 5) out = relu(sum_ks partial + bias)
    splitk_reduce<<<dim3(2048), 256, 0, stream>>>(partial, lin_b, out);
}